// Round 2
// baseline (1532.619 us; speedup 1.0000x reference)
//
#include <hip/hip_runtime.h>
#include <math.h>

#define B_ 16
#define L_ 4096
#define N_ 1024
#define D_ 256
#define NT 64
#define LT 64
#define QSTRIDE (D_ + 4)   // 260 floats: 4*QSTRIDE % 32 == 16 -> <=2-way on strided row reads
#define PSTRIDE (LT + 4)   // 68 floats, float4-aligned rows
#define EPS_ 1e-5f
#define NEG_ -1.0e9f
#define LOG2E_ 1.4426950408889634f

// Fused masked cross-attention + residual LayerNorm.
// One block = (batch b, 64 consecutive queries). Online softmax over L in
// 64-wide tiles staged in LDS. Thread map: tx = tid&15 (l / d lanes),
// ty = tid>>4 (n rows 4*ty+i). Mask is int32 (XLA bool -> int per harness).
__global__ __launch_bounds__(256)
void tgq_fused(const float* __restrict__ ef, const float* __restrict__ q,
               const int* __restrict__ msk,
               const float* __restrict__ gamma, const float* __restrict__ beta,
               float* __restrict__ out) {
  extern __shared__ float smem[];
  float* QL = smem;                    // NT * QSTRIDE floats (Q tile, persistent)
  float* EL = QL + NT * QSTRIDE;       // LT * QSTRIDE floats (exp_f tile)
  float* PL = EL + LT * QSTRIDE;       // NT * PSTRIDE floats (softmax P tile)

  const int tid = threadIdx.x;
  const int tx = tid & 15;
  const int ty = tid >> 4;
  const int b  = blockIdx.x >> 4;
  const int n0 = (blockIdx.x & 15) * NT;

  // ---- stage Q tile (once) ----
  {
    const float* qsrc = q + ((size_t)b * N_ + n0) * D_;
    for (int idx = tid; idx < NT * (D_ / 4); idx += 256) {
      int row = idx >> 6, c4 = idx & 63;
      float4 v = *reinterpret_cast<const float4*>(qsrc + (size_t)row * D_ + c4 * 4);
      *reinterpret_cast<float4*>(&QL[row * QSTRIDE + c4 * 4]) = v;
    }
  }

  float4 O4[4][4];                 // rows n0+4*ty+i ; cols d = 4*tx + 64*k
  float m_run[4], l_run[4];
  #pragma unroll
  for (int i = 0; i < 4; ++i) {
    m_run[i] = -INFINITY;
    l_run[i] = 0.f;
    #pragma unroll
    for (int k = 0; k < 4; ++k) O4[i][k] = make_float4(0.f, 0.f, 0.f, 0.f);
  }

  const float* efb = ef + (size_t)b * L_ * D_;
  const int* mb = msk + (size_t)b * L_ * N_;

  for (int t = 0; t < L_ / LT; ++t) {
    const int l0 = t * LT;
    __syncthreads();  // previous tile's EL/PL fully consumed

    // ---- stage E tile ----
    for (int idx = tid; idx < LT * (D_ / 4); idx += 256) {
      int row = idx >> 6, c4 = idx & 63;
      float4 v = *reinterpret_cast<const float4*>(efb + (size_t)(l0 + row) * D_ + c4 * 4);
      *reinterpret_cast<float4*>(&EL[row * QSTRIDE + c4 * 4]) = v;
    }
    // mask: int32 per element. For each of this thread's 4 l's, the 4 n's
    // n0+4*ty..+3 -> one aligned int4 load.
    int4 mv[4];
    #pragma unroll
    for (int j = 0; j < 4; ++j)
      mv[j] = *reinterpret_cast<const int4*>(
          mb + (size_t)(l0 + tx + 16 * j) * N_ + n0 + 4 * ty);
    __syncthreads();  // EL ready

    // ---- QK^T : s[i][j] = dot(E[l0+tx+16j], Q[n0+4ty+i]) ----
    float s0[4][4];
    #pragma unroll
    for (int i = 0; i < 4; ++i)
      #pragma unroll
      for (int j = 0; j < 4; ++j) s0[i][j] = 0.f;

    #pragma unroll 4
    for (int dq = 0; dq < D_ / 4; ++dq) {
      float4 qv[4], ev[4];
      #pragma unroll
      for (int i = 0; i < 4; ++i)
        qv[i] = *reinterpret_cast<const float4*>(&QL[(4 * ty + i) * QSTRIDE + dq * 4]);
      #pragma unroll
      for (int j = 0; j < 4; ++j)
        ev[j] = *reinterpret_cast<const float4*>(&EL[(tx + 16 * j) * QSTRIDE + dq * 4]);
      #pragma unroll
      for (int i = 0; i < 4; ++i)
        #pragma unroll
        for (int j = 0; j < 4; ++j) {
          s0[i][j] += qv[i].x * ev[j].x;
          s0[i][j] += qv[i].y * ev[j].y;
          s0[i][j] += qv[i].z * ev[j].z;
          s0[i][j] += qv[i].w * ev[j].w;
        }
    }

    // ---- scale + mask (mask True -> -1e9) ----
    const float scale = 0.0625f;  // 1/sqrt(256)
    #pragma unroll
    for (int i = 0; i < 4; ++i)
      #pragma unroll
      for (int j = 0; j < 4; ++j) {
        float v = s0[i][j] * scale;
        int mi = (i == 0) ? mv[j].x : (i == 1) ? mv[j].y : (i == 2) ? mv[j].z : mv[j].w;
        if (mi) v = NEG_;
        s0[i][j] = v;
      }

    // ---- online softmax update (row reduce across 16 tx lanes) ----
    #pragma unroll
    for (int i = 0; i < 4; ++i) {
      float mt = fmaxf(fmaxf(s0[i][0], s0[i][1]), fmaxf(s0[i][2], s0[i][3]));
      mt = fmaxf(mt, __shfl_xor(mt, 1));
      mt = fmaxf(mt, __shfl_xor(mt, 2));
      mt = fmaxf(mt, __shfl_xor(mt, 4));
      mt = fmaxf(mt, __shfl_xor(mt, 8));
      float mn = fmaxf(m_run[i], mt);
      float alpha = __builtin_amdgcn_exp2f((m_run[i] - mn) * LOG2E_);
      float ts = 0.f;
      #pragma unroll
      for (int j = 0; j < 4; ++j) {
        float p = __builtin_amdgcn_exp2f((s0[i][j] - mn) * LOG2E_);
        s0[i][j] = p;
        ts += p;
      }
      ts += __shfl_xor(ts, 1);
      ts += __shfl_xor(ts, 2);
      ts += __shfl_xor(ts, 4);
      ts += __shfl_xor(ts, 8);
      l_run[i] = l_run[i] * alpha + ts;
      m_run[i] = mn;
      #pragma unroll
      for (int k = 0; k < 4; ++k) {
        O4[i][k].x *= alpha; O4[i][k].y *= alpha;
        O4[i][k].z *= alpha; O4[i][k].w *= alpha;
      }
    }

    // ---- write P to LDS ----
    #pragma unroll
    for (int i = 0; i < 4; ++i)
      #pragma unroll
      for (int j = 0; j < 4; ++j)
        PL[(4 * ty + i) * PSTRIDE + tx + 16 * j] = s0[i][j];
    __syncthreads();  // PL ready

    // ---- PV: O[n][d] += P[n][l] * E[l][d] ----
    #pragma unroll 2
    for (int l4 = 0; l4 < LT / 4; ++l4) {
      float4 p4[4];
      #pragma unroll
      for (int i = 0; i < 4; ++i)
        p4[i] = *reinterpret_cast<const float4*>(&PL[(4 * ty + i) * PSTRIDE + 4 * l4]);
      #pragma unroll
      for (int c = 0; c < 4; ++c) {
        float4 e4[4];
        #pragma unroll
        for (int k = 0; k < 4; ++k)
          e4[k] = *reinterpret_cast<const float4*>(
              &EL[(4 * l4 + c) * QSTRIDE + 4 * tx + 64 * k]);
        #pragma unroll
        for (int i = 0; i < 4; ++i) {
          float pc = (c == 0) ? p4[i].x : (c == 1) ? p4[i].y : (c == 2) ? p4[i].z : p4[i].w;
          #pragma unroll
          for (int k = 0; k < 4; ++k) {
            O4[i][k].x += pc * e4[k].x;
            O4[i][k].y += pc * e4[k].y;
            O4[i][k].z += pc * e4[k].z;
            O4[i][k].w += pc * e4[k].w;
          }
        }
      }
    }
  }

  // ---- epilogue: out = LayerNorm(Q + O / l_run) ----
  const float inv256 = 1.f / 256.f;
  float* outb = out + ((size_t)b * N_ + n0) * D_;
  #pragma unroll
  for (int i = 0; i < 4; ++i) {
    const int row = 4 * ty + i;
    const float inv_l = 1.f / l_run[i];
    float4 xv[4];
    float sum = 0.f;
    #pragma unroll
    for (int k = 0; k < 4; ++k) {
      const int d = 4 * tx + 64 * k;
      float4 qv = *reinterpret_cast<const float4*>(&QL[row * QSTRIDE + d]);
      xv[k].x = qv.x + O4[i][k].x * inv_l;
      xv[k].y = qv.y + O4[i][k].y * inv_l;
      xv[k].z = qv.z + O4[i][k].z * inv_l;
      xv[k].w = qv.w + O4[i][k].w * inv_l;
      sum += xv[k].x + xv[k].y + xv[k].z + xv[k].w;
    }
    sum += __shfl_xor(sum, 1);
    sum += __shfl_xor(sum, 2);
    sum += __shfl_xor(sum, 4);
    sum += __shfl_xor(sum, 8);
    const float mu = sum * inv256;
    float s2 = 0.f;
    #pragma unroll
    for (int k = 0; k < 4; ++k) {
      float dx;
      dx = xv[k].x - mu; s2 += dx * dx;
      dx = xv[k].y - mu; s2 += dx * dx;
      dx = xv[k].z - mu; s2 += dx * dx;
      dx = xv[k].w - mu; s2 += dx * dx;
    }
    s2 += __shfl_xor(s2, 1);
    s2 += __shfl_xor(s2, 2);
    s2 += __shfl_xor(s2, 4);
    s2 += __shfl_xor(s2, 8);
    const float rs = rsqrtf(s2 * inv256 + EPS_);
    #pragma unroll
    for (int k = 0; k < 4; ++k) {
      const int d = 4 * tx + 64 * k;
      float4 g  = *reinterpret_cast<const float4*>(gamma + d);
      float4 be = *reinterpret_cast<const float4*>(beta + d);
      float4 y;
      y.x = (xv[k].x - mu) * rs * g.x + be.x;
      y.y = (xv[k].y - mu) * rs * g.y + be.y;
      y.z = (xv[k].z - mu) * rs * g.z + be.z;
      y.w = (xv[k].w - mu) * rs * g.w + be.w;
      *reinterpret_cast<float4*>(outb + (size_t)row * D_ + d) = y;
    }
  }
}

extern "C" void kernel_launch(void* const* d_in, const int* in_sizes, int n_in,
                              void* d_out, int out_size, void* d_ws, size_t ws_size,
                              hipStream_t stream) {
  const float* ef    = (const float*)d_in[0];
  const float* q     = (const float*)d_in[1];
  const int*   m     = (const int*)d_in[2];    // XLA bool -> int32 per harness
  const float* gamma = (const float*)d_in[3];
  const float* beta  = (const float*)d_in[4];
  float* out         = (float*)d_out;

  const size_t lds_bytes =
      (size_t)(NT * QSTRIDE + LT * QSTRIDE + NT * PSTRIDE) * sizeof(float);  // 150528 B

  // >64 KB dynamic LDS needs the attribute bump; idempotent, host-side, capture-safe.
  (void)hipFuncSetAttribute(reinterpret_cast<const void*>(tgq_fused),
                            hipFuncAttributeMaxDynamicSharedMemorySize,
                            (int)lds_bytes);

  tgq_fused<<<dim3(B_ * (N_ / NT)), dim3(256), lds_bytes, stream>>>(
      ef, q, m, gamma, beta, out);
}

// Round 3
// 389.960 us; speedup vs baseline: 3.9302x; 3.9302x over previous
//
#include <hip/hip_runtime.h>
#include <hip/hip_bf16.h>
#include <math.h>

typedef short bf16x8 __attribute__((ext_vector_type(8)));
typedef float f32x4 __attribute__((ext_vector_type(4)));
typedef unsigned int u32;

#define B_ 16
#define L_ 4096
#define N_ 1024
#define D_ 256
#define ESTR 264   // E_lds row stride (elems): 528B, 16B-aligned, 2-way banks
#define TSTR 72    // ET_lds row stride: 144B
#define PSTR 72    // P_lds row stride: 144B
#define EPS_ 1e-5f
#define NEG_ -1.0e9f
#define LOG2E_ 1.4426950408889634f

__device__ __forceinline__ u32 pk2(float x, float y) {
  __hip_bfloat16 hx = __float2bfloat16(x), hy = __float2bfloat16(y);
  return (u32)reinterpret_cast<unsigned short&>(hx) |
         ((u32)reinterpret_cast<unsigned short&>(hy) << 16);
}

// ---------------- prep: f32 E -> bf16 E (row-major) + bf16 E^T ----------------
__global__ __launch_bounds__(256)
void prep_kernel(const float* __restrict__ ef, __hip_bfloat16* __restrict__ et,
                 __hip_bfloat16* __restrict__ ebf, int write_ebf) {
  __shared__ float T[64][65];
  const int tid = threadIdx.x;
  const int bid = blockIdx.x;
  const int b  = bid >> 8;
  const int lt = (bid >> 2) & 63;
  const int dt = bid & 3;

  {  // read 64x64 f32 tile (coalesced rows), stash to LDS, also emit bf16 row-major
    const int r = tid & 63, s = tid >> 6;
    const float* src = ef + ((size_t)b * L_ + lt * 64 + r) * D_ + dt * 64 + s * 16;
    float v[16];
    #pragma unroll
    for (int k = 0; k < 4; ++k) {
      float4 f = *reinterpret_cast<const float4*>(src + 4 * k);
      v[4*k] = f.x; v[4*k+1] = f.y; v[4*k+2] = f.z; v[4*k+3] = f.w;
    }
    #pragma unroll
    for (int m = 0; m < 16; ++m) T[r][s * 16 + m] = v[m];
    if (write_ebf) {
      u32 w[8];
      #pragma unroll
      for (int p = 0; p < 8; ++p) w[p] = pk2(v[2*p], v[2*p+1]);
      __hip_bfloat16* dst = ebf + ((size_t)b * L_ + lt * 64 + r) * D_ + dt * 64 + s * 16;
      *reinterpret_cast<uint4*>(dst)     = *reinterpret_cast<uint4*>(&w[0]);
      *reinterpret_cast<uint4*>(dst + 8) = *reinterpret_cast<uint4*>(&w[4]);
    }
  }
  __syncthreads();
  {  // transposed read, write bf16 E^T rows (d-major)
    const int dcol = tid & 63, s2 = tid >> 6;
    float v[16];
    #pragma unroll
    for (int m = 0; m < 16; ++m) v[m] = T[s2 * 16 + m][dcol];
    u32 w[8];
    #pragma unroll
    for (int p = 0; p < 8; ++p) w[p] = pk2(v[2*p], v[2*p+1]);
    __hip_bfloat16* dst = et + ((size_t)b * D_ + dt * 64 + dcol) * L_ + lt * 64 + s2 * 16;
    *reinterpret_cast<uint4*>(dst)     = *reinterpret_cast<uint4*>(&w[0]);
    *reinterpret_cast<uint4*>(dst + 8) = *reinterpret_cast<uint4*>(&w[4]);
  }
}

// ---------------- main: MFMA flash attention + residual LayerNorm ----------------
// Block = (batch, 64 queries), 4 waves x 16 q. Swapped QK^T (A=E, B=Q), so softmax
// over l is in-lane; P bounced via wave-private LDS into PV A-frags; E^T tile gives
// row-contiguous PV B-frags. All LDS strides 16B-aligned, <=2-way banks.
__global__ __launch_bounds__(256)
void attn_kernel(const float* __restrict__ ef, const float* __restrict__ q,
                 const int* __restrict__ msk, const float* __restrict__ gamma,
                 const float* __restrict__ beta, const __hip_bfloat16* __restrict__ et,
                 const __hip_bfloat16* __restrict__ ebf, int use_ebf,
                 float* __restrict__ out) {
  extern __shared__ char smem[];
  __hip_bfloat16* EL  = (__hip_bfloat16*)smem;   // [64][ESTR]
  __hip_bfloat16* TL  = EL + 64 * ESTR;          // [256][TSTR]
  __hip_bfloat16* PLb = TL + 256 * TSTR;         // [4][16][PSTR]

  const int tid  = threadIdx.x;
  const int wid  = tid >> 6;
  const int lane = tid & 63;
  const int g    = lane >> 4;
  const int c    = lane & 15;

  const int raw = blockIdx.x;
  const int bs  = (raw & 7) * 32 + (raw >> 3);   // XCD-chunked swizzle (256 % 8 == 0)
  const int b   = bs >> 4;
  const int n0  = (bs & 15) * 64;
  const int n0w = n0 + wid * 16;

  // ---- hoist Q fragments: B[k=d][j=n]: lane holds Q[n0w+c][32dk+8g+i] ----
  bf16x8 qf[8];
  {
    const float* qrow = q + ((size_t)b * N_ + n0w + c) * D_;
    #pragma unroll
    for (int dk = 0; dk < 8; ++dk) {
      float4 a  = *reinterpret_cast<const float4*>(qrow + 32 * dk + 8 * g);
      float4 b2 = *reinterpret_cast<const float4*>(qrow + 32 * dk + 8 * g + 4);
      u32 w[4] = {pk2(a.x, a.y), pk2(a.z, a.w), pk2(b2.x, b2.y), pk2(b2.z, b2.w)};
      qf[dk] = *reinterpret_cast<bf16x8*>(w);
    }
  }

  f32x4 oacc[16];
  #pragma unroll
  for (int j = 0; j < 16; ++j) oacc[j] = (f32x4){0.f, 0.f, 0.f, 0.f};
  float m_run = -INFINITY, l_run = 0.f;

  __hip_bfloat16* PLw = PLb + wid * 16 * PSTR;
  const float scale = 0.0625f;

  for (int t64 = 0; t64 < L_ / 64; ++t64) {
    const int l0 = t64 * 64;

    // mask loads early (global, overlap with staging)
    int mv[16];
    #pragma unroll
    for (int t = 0; t < 4; ++t)
      #pragma unroll
      for (int r = 0; r < 4; ++r)
        mv[4*t+r] = msk[((size_t)b * L_ + l0 + 16*t + 4*g + r) * N_ + n0w + c];

    __syncthreads();  // previous tile fully consumed

    // ---- stage E tile (row-major bf16) ----
    {
      const int row = tid & 63, sg = tid >> 6;
      if (use_ebf) {
        const __hip_bfloat16* src = ebf + ((size_t)b * L_ + l0 + row) * D_ + sg * 64;
        #pragma unroll
        for (int p = 0; p < 8; ++p)
          *reinterpret_cast<uint4*>(EL + row * ESTR + sg * 64 + p * 8) =
              *reinterpret_cast<const uint4*>(src + p * 8);
      } else {
        const float* src = ef + ((size_t)b * L_ + l0 + row) * D_ + sg * 64;
        #pragma unroll
        for (int p = 0; p < 8; ++p) {
          float4 a  = *reinterpret_cast<const float4*>(src + p * 8);
          float4 b2 = *reinterpret_cast<const float4*>(src + p * 8 + 4);
          u32 w[4] = {pk2(a.x, a.y), pk2(a.z, a.w), pk2(b2.x, b2.y), pk2(b2.z, b2.w)};
          *reinterpret_cast<uint4*>(EL + row * ESTR + sg * 64 + p * 8) =
              *reinterpret_cast<uint4*>(w);
        }
      }
    }
    // ---- stage E^T tile ----
    {
      const __hip_bfloat16* src = et + ((size_t)b * D_ + tid) * L_ + l0;
      #pragma unroll
      for (int p = 0; p < 8; ++p)
        *reinterpret_cast<uint4*>(TL + tid * TSTR + p * 8) =
            *reinterpret_cast<const uint4*>(src + p * 8);
    }
    __syncthreads();  // tiles ready

    // ---- QK^T (swapped): S^T[l][n], A=E, B=Q ----
    float sv[16];
    #pragma unroll
    for (int t = 0; t < 4; ++t) {
      f32x4 sacc = (f32x4){0.f, 0.f, 0.f, 0.f};
      #pragma unroll
      for (int dk = 0; dk < 8; ++dk) {
        bf16x8 af = *reinterpret_cast<const bf16x8*>(EL + (16*t + c) * ESTR + 32*dk + 8*g);
        sacc = __builtin_amdgcn_mfma_f32_16x16x32_bf16(af, qf[dk], sacc, 0, 0, 0);
      }
      #pragma unroll
      for (int r = 0; r < 4; ++r) {
        float v = sacc[r] * scale;
        if (mv[4*t+r]) v = NEG_;
        sv[4*t+r] = v;
      }
    }

    // ---- online softmax (lane owns n=c; rows l = 16t+4g+r) ----
    float tm = sv[0];
    #pragma unroll
    for (int i = 1; i < 16; ++i) tm = fmaxf(tm, sv[i]);
    tm = fmaxf(tm, __shfl_xor(tm, 16));
    tm = fmaxf(tm, __shfl_xor(tm, 32));
    const float m_new = fmaxf(m_run, tm);
    const float alpha = __builtin_amdgcn_exp2f((m_run - m_new) * LOG2E_);
    float ts = 0.f;
    #pragma unroll
    for (int i = 0; i < 16; ++i) {
      sv[i] = __builtin_amdgcn_exp2f((sv[i] - m_new) * LOG2E_);
      ts += sv[i];
    }
    ts += __shfl_xor(ts, 16);
    ts += __shfl_xor(ts, 32);
    l_run = l_run * alpha + ts;
    m_run = m_new;

    // rescale O accumulator (rows n=4g+r need alpha from lane 4g+r)
    float ar[4];
    #pragma unroll
    for (int r = 0; r < 4; ++r) ar[r] = __shfl(alpha, 4*g + r, 64);
    #pragma unroll
    for (int j = 0; j < 16; ++j)
      #pragma unroll
      for (int r = 0; r < 4; ++r) oacc[j][r] *= ar[r];

    // ---- P -> wave-private LDS (bf16), layout [n=c][l] ----
    #pragma unroll
    for (int t = 0; t < 4; ++t) {
      uint2 w;
      w.x = pk2(sv[4*t+0], sv[4*t+1]);
      w.y = pk2(sv[4*t+2], sv[4*t+3]);
      *reinterpret_cast<uint2*>(PLw + c * PSTR + 16*t + 4*g) = w;
    }

    // ---- PV: O[n][d] += P[n][l] * E[l][d]; A=P, B=E^T rows ----
    #pragma unroll
    for (int h = 0; h < 2; ++h) {
      bf16x8 pa = *reinterpret_cast<const bf16x8*>(PLw + c * PSTR + 32*h + 8*g);
      #pragma unroll
      for (int j = 0; j < 16; ++j) {
        bf16x8 bfr = *reinterpret_cast<const bf16x8*>(TL + (16*j + c) * TSTR + 32*h + 8*g);
        oacc[j] = __builtin_amdgcn_mfma_f32_16x16x32_bf16(pa, bfr, oacc[j], 0, 0, 0);
      }
    }
  }

  // ---- epilogue: out = LayerNorm(Q + O/l) ----
  float invl[4];
  #pragma unroll
  for (int r = 0; r < 4; ++r) invl[r] = 1.f / __shfl(l_run, 4*g + r, 64);
  float gv[16], bv[16];
  #pragma unroll
  for (int j = 0; j < 16; ++j) { gv[j] = gamma[16*j + c]; bv[j] = beta[16*j + c]; }
  const float* qb = q + ((size_t)b * N_ + n0w) * D_;
  float* ob = out + ((size_t)b * N_ + n0w) * D_;
  const float inv256 = 1.f / 256.f;
  #pragma unroll
  for (int r = 0; r < 4; ++r) {
    const int n = 4*g + r;
    float x[16], s = 0.f;
    #pragma unroll
    for (int j = 0; j < 16; ++j) {
      x[j] = qb[(size_t)n * D_ + 16*j + c] + oacc[j][r] * invl[r];
      s += x[j];
    }
    s += __shfl_xor(s, 1); s += __shfl_xor(s, 2);
    s += __shfl_xor(s, 4); s += __shfl_xor(s, 8);
    const float mu = s * inv256;
    float v2 = 0.f;
    #pragma unroll
    for (int j = 0; j < 16; ++j) { float d = x[j] - mu; v2 += d * d; }
    v2 += __shfl_xor(v2, 1); v2 += __shfl_xor(v2, 2);
    v2 += __shfl_xor(v2, 4); v2 += __shfl_xor(v2, 8);
    const float rs = rsqrtf(v2 * inv256 + EPS_);
    #pragma unroll
    for (int j = 0; j < 16; ++j)
      ob[(size_t)n * D_ + 16*j + c] = (x[j] - mu) * rs * gv[j] + bv[j];
  }
}

// ---------------- fallback (round-2 proven f32 kernel) ----------------
#define QSTRIDE (D_ + 4)
#define PSTRIDE (64 + 4)
__global__ __launch_bounds__(256)
void tgq_fallback(const float* __restrict__ ef, const float* __restrict__ q,
                  const int* __restrict__ msk, const float* __restrict__ gamma,
                  const float* __restrict__ beta, float* __restrict__ out) {
  extern __shared__ float fsm[];
  float* QL = fsm;
  float* EL = QL + 64 * QSTRIDE;
  float* PL = EL + 64 * QSTRIDE;
  const int tid = threadIdx.x, tx = tid & 15, ty = tid >> 4;
  const int b = blockIdx.x >> 4, n0 = (blockIdx.x & 15) * 64;
  {
    const float* qsrc = q + ((size_t)b * N_ + n0) * D_;
    for (int idx = tid; idx < 64 * 64; idx += 256) {
      int row = idx >> 6, c4 = idx & 63;
      *reinterpret_cast<float4*>(&QL[row * QSTRIDE + c4 * 4]) =
          *reinterpret_cast<const float4*>(qsrc + (size_t)row * D_ + c4 * 4);
    }
  }
  float4 O4[4][4]; float m_run[4], l_run[4];
  #pragma unroll
  for (int i = 0; i < 4; ++i) {
    m_run[i] = -INFINITY; l_run[i] = 0.f;
    #pragma unroll
    for (int k = 0; k < 4; ++k) O4[i][k] = make_float4(0.f, 0.f, 0.f, 0.f);
  }
  const float* efb = ef + (size_t)b * L_ * D_;
  const int* mb = msk + (size_t)b * L_ * N_;
  for (int t = 0; t < L_ / 64; ++t) {
    const int l0 = t * 64;
    __syncthreads();
    for (int idx = tid; idx < 64 * 64; idx += 256) {
      int row = idx >> 6, c4 = idx & 63;
      *reinterpret_cast<float4*>(&EL[row * QSTRIDE + c4 * 4]) =
          *reinterpret_cast<const float4*>(efb + (size_t)(l0 + row) * D_ + c4 * 4);
    }
    int4 mvv[4];
    #pragma unroll
    for (int j = 0; j < 4; ++j)
      mvv[j] = *reinterpret_cast<const int4*>(mb + (size_t)(l0 + tx + 16*j) * N_ + n0 + 4*ty);
    __syncthreads();
    float s0[4][4];
    #pragma unroll
    for (int i = 0; i < 4; ++i)
      #pragma unroll
      for (int j = 0; j < 4; ++j) s0[i][j] = 0.f;
    #pragma unroll 4
    for (int dq = 0; dq < 64; ++dq) {
      float4 qv[4], ev[4];
      #pragma unroll
      for (int i = 0; i < 4; ++i)
        qv[i] = *reinterpret_cast<const float4*>(&QL[(4*ty+i) * QSTRIDE + dq*4]);
      #pragma unroll
      for (int j = 0; j < 4; ++j)
        ev[j] = *reinterpret_cast<const float4*>(&EL[(tx+16*j) * QSTRIDE + dq*4]);
      #pragma unroll
      for (int i = 0; i < 4; ++i)
        #pragma unroll
        for (int j = 0; j < 4; ++j)
          s0[i][j] += qv[i].x*ev[j].x + qv[i].y*ev[j].y + qv[i].z*ev[j].z + qv[i].w*ev[j].w;
    }
    #pragma unroll
    for (int i = 0; i < 4; ++i)
      #pragma unroll
      for (int j = 0; j < 4; ++j) {
        float v = s0[i][j] * 0.0625f;
        int mi = (i==0)?mvv[j].x:(i==1)?mvv[j].y:(i==2)?mvv[j].z:mvv[j].w;
        if (mi) v = NEG_;
        s0[i][j] = v;
      }
    #pragma unroll
    for (int i = 0; i < 4; ++i) {
      float mt = fmaxf(fmaxf(s0[i][0], s0[i][1]), fmaxf(s0[i][2], s0[i][3]));
      mt = fmaxf(mt, __shfl_xor(mt,1)); mt = fmaxf(mt, __shfl_xor(mt,2));
      mt = fmaxf(mt, __shfl_xor(mt,4)); mt = fmaxf(mt, __shfl_xor(mt,8));
      float mn = fmaxf(m_run[i], mt);
      float alpha = __builtin_amdgcn_exp2f((m_run[i] - mn) * LOG2E_);
      float tsum = 0.f;
      #pragma unroll
      for (int j = 0; j < 4; ++j) {
        float p = __builtin_amdgcn_exp2f((s0[i][j] - mn) * LOG2E_);
        s0[i][j] = p; tsum += p;
      }
      tsum += __shfl_xor(tsum,1); tsum += __shfl_xor(tsum,2);
      tsum += __shfl_xor(tsum,4); tsum += __shfl_xor(tsum,8);
      l_run[i] = l_run[i] * alpha + tsum; m_run[i] = mn;
      #pragma unroll
      for (int k = 0; k < 4; ++k) {
        O4[i][k].x *= alpha; O4[i][k].y *= alpha; O4[i][k].z *= alpha; O4[i][k].w *= alpha;
      }
    }
    #pragma unroll
    for (int i = 0; i < 4; ++i)
      #pragma unroll
      for (int j = 0; j < 4; ++j)
        PL[(4*ty+i) * PSTRIDE + tx + 16*j] = s0[i][j];
    __syncthreads();
    #pragma unroll 2
    for (int l4 = 0; l4 < 16; ++l4) {
      float4 p4[4];
      #pragma unroll
      for (int i = 0; i < 4; ++i)
        p4[i] = *reinterpret_cast<const float4*>(&PL[(4*ty+i) * PSTRIDE + 4*l4]);
      #pragma unroll
      for (int cc = 0; cc < 4; ++cc) {
        float4 e4[4];
        #pragma unroll
        for (int k = 0; k < 4; ++k)
          e4[k] = *reinterpret_cast<const float4*>(&EL[(4*l4+cc) * QSTRIDE + 4*tx + 64*k]);
        #pragma unroll
        for (int i = 0; i < 4; ++i) {
          float pc = (cc==0)?p4[i].x:(cc==1)?p4[i].y:(cc==2)?p4[i].z:p4[i].w;
          #pragma unroll
          for (int k = 0; k < 4; ++k) {
            O4[i][k].x += pc*e4[k].x; O4[i][k].y += pc*e4[k].y;
            O4[i][k].z += pc*e4[k].z; O4[i][k].w += pc*e4[k].w;
          }
        }
      }
    }
  }
  const float inv256 = 1.f / 256.f;
  float* outb = out + ((size_t)b * N_ + n0) * D_;
  #pragma unroll
  for (int i = 0; i < 4; ++i) {
    const int row = 4*ty + i;
    const float inv_l = 1.f / l_run[i];
    float4 xv[4]; float sum = 0.f;
    #pragma unroll
    for (int k = 0; k < 4; ++k) {
      const int d = 4*tx + 64*k;
      float4 qv = *reinterpret_cast<const float4*>(&QL[row * QSTRIDE + d]);
      xv[k].x = qv.x + O4[i][k].x*inv_l; xv[k].y = qv.y + O4[i][k].y*inv_l;
      xv[k].z = qv.z + O4[i][k].z*inv_l; xv[k].w = qv.w + O4[i][k].w*inv_l;
      sum += xv[k].x + xv[k].y + xv[k].z + xv[k].w;
    }
    sum += __shfl_xor(sum,1); sum += __shfl_xor(sum,2);
    sum += __shfl_xor(sum,4); sum += __shfl_xor(sum,8);
    const float mu = sum * inv256;
    float s2 = 0.f;
    #pragma unroll
    for (int k = 0; k < 4; ++k) {
      float dx;
      dx = xv[k].x-mu; s2 += dx*dx; dx = xv[k].y-mu; s2 += dx*dx;
      dx = xv[k].z-mu; s2 += dx*dx; dx = xv[k].w-mu; s2 += dx*dx;
    }
    s2 += __shfl_xor(s2,1); s2 += __shfl_xor(s2,2);
    s2 += __shfl_xor(s2,4); s2 += __shfl_xor(s2,8);
    const float rs = rsqrtf(s2 * inv256 + EPS_);
    #pragma unroll
    for (int k = 0; k < 4; ++k) {
      const int d = 4*tx + 64*k;
      float4 gg = *reinterpret_cast<const float4*>(gamma + d);
      float4 be = *reinterpret_cast<const float4*>(beta + d);
      float4 y;
      y.x = (xv[k].x-mu)*rs*gg.x + be.x; y.y = (xv[k].y-mu)*rs*gg.y + be.y;
      y.z = (xv[k].z-mu)*rs*gg.z + be.z; y.w = (xv[k].w-mu)*rs*gg.w + be.w;
      *reinterpret_cast<float4*>(outb + (size_t)row * D_ + d) = y;
    }
  }
}

extern "C" void kernel_launch(void* const* d_in, const int* in_sizes, int n_in,
                              void* d_out, int out_size, void* d_ws, size_t ws_size,
                              hipStream_t stream) {
  const float* ef    = (const float*)d_in[0];
  const float* q     = (const float*)d_in[1];
  const int*   m     = (const int*)d_in[2];
  const float* gamma = (const float*)d_in[3];
  const float* beta  = (const float*)d_in[4];
  float* out         = (float*)d_out;

  const size_t et_bytes  = (size_t)B_ * D_ * L_ * sizeof(__hip_bfloat16);  // 33.5 MB
  const size_t ebf_bytes = (size_t)B_ * L_ * D_ * sizeof(__hip_bfloat16);  // 33.5 MB

  if (ws_size < et_bytes) {
    // workspace too small for the MFMA path: proven f32 fallback
    const size_t lds = (size_t)(64*QSTRIDE + 64*QSTRIDE + 64*PSTRIDE) * sizeof(float);
    (void)hipFuncSetAttribute(reinterpret_cast<const void*>(tgq_fallback),
                              hipFuncAttributeMaxDynamicSharedMemorySize, (int)lds);
    tgq_fallback<<<dim3(256), dim3(256), lds, stream>>>(ef, q, m, gamma, beta, out);
    return;
  }

  __hip_bfloat16* et  = (__hip_bfloat16*)d_ws;
  int use_ebf = (ws_size >= et_bytes + ebf_bytes) ? 1 : 0;
  __hip_bfloat16* ebf = use_ebf ? (et + (size_t)B_ * D_ * L_) : nullptr;

  prep_kernel<<<dim3(4096), dim3(256), 0, stream>>>(ef, et, ebf, use_ebf);

  const size_t lds_bytes = (size_t)(64 * ESTR + 256 * TSTR + 4 * 16 * PSTR) * 2;  // 79872
  (void)hipFuncSetAttribute(reinterpret_cast<const void*>(attn_kernel),
                            hipFuncAttributeMaxDynamicSharedMemorySize, (int)lds_bytes);
  attn_kernel<<<dim3(256), dim3(256), lds_bytes, stream>>>(
      ef, q, m, gamma, beta, et, ebf, use_ebf, out);
}

// Round 4
// 342.981 us; speedup vs baseline: 4.4685x; 1.1370x over previous
//
#include <hip/hip_runtime.h>
#include <hip/hip_bf16.h>
#include <math.h>

typedef short bf16x8 __attribute__((ext_vector_type(8)));
typedef float f32x4 __attribute__((ext_vector_type(4)));
typedef unsigned int u32;

#define B_ 16
#define L_ 4096
#define N_ 1024
#define D_ 256
#define EPS_ 1e-5f
#define NEG_ -1.0e9f
#define LOG2E_ 1.4426950408889634f

// round-3 single-kernel tile params (middle tier)
#define ESTR 264
#define TSTR 72
#define PSTR 72
// split-path tile params
#define LBLK 32
#define ESTR2 264   // EL row stride elems (528B = 33 x 16B slots, odd -> 2-way max)
#define TSTR2 40    // TL row stride elems (80B = 5 slots, odd)
#define PSTR2 40

__device__ __forceinline__ u32 pk2(float x, float y) {
  __hip_bfloat16 hx = __float2bfloat16(x), hy = __float2bfloat16(y);
  return (u32)reinterpret_cast<unsigned short&>(hx) |
         ((u32)reinterpret_cast<unsigned short&>(hy) << 16);
}

// ---------------- prep: f32 E -> bf16 E^T (+ optional bf16 E row-major) ----------------
__global__ __launch_bounds__(256)
void prep_kernel(const float* __restrict__ ef, __hip_bfloat16* __restrict__ et,
                 __hip_bfloat16* __restrict__ ebf, int write_ebf) {
  __shared__ float T[64][65];
  const int tid = threadIdx.x;
  const int bid = blockIdx.x;
  const int b  = bid >> 8;
  const int lt = (bid >> 2) & 63;
  const int dt = bid & 3;
  {
    const int r = tid & 63, s = tid >> 6;
    const float* src = ef + ((size_t)b * L_ + lt * 64 + r) * D_ + dt * 64 + s * 16;
    float v[16];
    #pragma unroll
    for (int k = 0; k < 4; ++k) {
      float4 f = *reinterpret_cast<const float4*>(src + 4 * k);
      v[4*k] = f.x; v[4*k+1] = f.y; v[4*k+2] = f.z; v[4*k+3] = f.w;
    }
    #pragma unroll
    for (int m = 0; m < 16; ++m) T[r][s * 16 + m] = v[m];
    if (write_ebf) {
      u32 w[8];
      #pragma unroll
      for (int p = 0; p < 8; ++p) w[p] = pk2(v[2*p], v[2*p+1]);
      __hip_bfloat16* dst = ebf + ((size_t)b * L_ + lt * 64 + r) * D_ + dt * 64 + s * 16;
      *reinterpret_cast<uint4*>(dst)     = *reinterpret_cast<uint4*>(&w[0]);
      *reinterpret_cast<uint4*>(dst + 8) = *reinterpret_cast<uint4*>(&w[4]);
    }
  }
  __syncthreads();
  {
    const int dcol = tid & 63, s2 = tid >> 6;
    float v[16];
    #pragma unroll
    for (int m = 0; m < 16; ++m) v[m] = T[s2 * 16 + m][dcol];
    u32 w[8];
    #pragma unroll
    for (int p = 0; p < 8; ++p) w[p] = pk2(v[2*p], v[2*p+1]);
    __hip_bfloat16* dst = et + ((size_t)b * D_ + dt * 64 + dcol) * L_ + lt * 64 + s2 * 16;
    *reinterpret_cast<uint4*>(dst)     = *reinterpret_cast<uint4*>(&w[0]);
    *reinterpret_cast<uint4*>(dst + 8) = *reinterpret_cast<uint4*>(&w[4]);
  }
}

// ---------------- phase 1: partial flash attention over an L-chunk ----------------
// Block = (b, 64-query tile, L-split s). 4 waves x 16 q. Writes un-normalized
// O-partial + running (m, l) to workspace. MFMA fragment math identical to the
// validated round-3 kernel; tiles shrunk to LBLK=32 so LDS=41.5KB -> 3 blocks/CU.
__global__ __launch_bounds__(256)
void attn_part(const float* __restrict__ ef, const float* __restrict__ q,
               const int* __restrict__ msk, const __hip_bfloat16* __restrict__ et,
               const __hip_bfloat16* __restrict__ ebf, int use_ebf,
               int slog, float* __restrict__ opart,
               float* __restrict__ mpart, float* __restrict__ lpart) {
  extern __shared__ char smem[];
  __hip_bfloat16* EL  = (__hip_bfloat16*)smem;     // [LBLK][ESTR2]
  __hip_bfloat16* TL  = EL + LBLK * ESTR2;         // [256][TSTR2]
  __hip_bfloat16* PLb = TL + 256 * TSTR2;          // [4][16][PSTR2]

  const int tid  = threadIdx.x;
  const int wid  = tid >> 6;
  const int lane = tid & 63;
  const int g    = lane >> 4;
  const int c    = lane & 15;

  const int S   = 1 << slog;
  const int nb  = 256 << slog;          // gridDim.x
  const int raw = blockIdx.x;
  const int cpx = nb >> 3;
  const int bs  = (raw & 7) * cpx + (raw >> 3);   // XCD-chunked swizzle
  const int nt   = bs & 15;
  const int rest = bs >> 4;             // = b*S + s
  const int s    = rest & (S - 1);
  const int b    = rest >> slog;

  const int lsplit = L_ >> slog;
  const int lbase  = s * lsplit;
  const int n0w    = nt * 64 + wid * 16;

  // ---- hoist Q fragments: lane holds Q[n0w+c][32dk+8g+i] ----
  bf16x8 qf[8];
  {
    const float* qrow = q + ((size_t)b * N_ + n0w + c) * D_;
    #pragma unroll
    for (int dk = 0; dk < 8; ++dk) {
      float4 a  = *reinterpret_cast<const float4*>(qrow + 32 * dk + 8 * g);
      float4 b2 = *reinterpret_cast<const float4*>(qrow + 32 * dk + 8 * g + 4);
      u32 w[4] = {pk2(a.x, a.y), pk2(a.z, a.w), pk2(b2.x, b2.y), pk2(b2.z, b2.w)};
      qf[dk] = *reinterpret_cast<bf16x8*>(w);
    }
  }

  f32x4 oacc[16];
  #pragma unroll
  for (int j = 0; j < 16; ++j) oacc[j] = (f32x4){0.f, 0.f, 0.f, 0.f};
  float m_run = -INFINITY, l_run = 0.f;

  __hip_bfloat16* PLw = PLb + wid * 16 * PSTR2;
  const float scale = 0.0625f;
  const int ntiles = lsplit / LBLK;

  for (int t = 0; t < ntiles; ++t) {
    const int l0 = lbase + t * LBLK;

    // mask loads early (global; per lane: n = n0w+c, l = l0+16tt+4g+r)
    int mv[8];
    #pragma unroll
    for (int tt = 0; tt < 2; ++tt)
      #pragma unroll
      for (int r = 0; r < 4; ++r)
        mv[4*tt+r] = msk[((size_t)b * L_ + l0 + 16*tt + 4*g + r) * N_ + n0w + c];

    __syncthreads();  // previous tile fully consumed

    // ---- stage EL [32][256] via 16B units (unit = tid + 256p) ----
    #pragma unroll
    for (int p = 0; p < 4; ++p) {
      const int unit = tid + 256 * p;
      const int row = unit >> 5, iu = unit & 31;
      if (use_ebf) {
        *reinterpret_cast<uint4*>(EL + row * ESTR2 + iu * 8) =
            *reinterpret_cast<const uint4*>(ebf + ((size_t)b * L_ + l0 + row) * D_ + iu * 8);
      } else {
        const float* src = ef + ((size_t)b * L_ + l0 + row) * D_ + iu * 8;
        float4 a  = *reinterpret_cast<const float4*>(src);
        float4 b2 = *reinterpret_cast<const float4*>(src + 4);
        u32 w[4] = {pk2(a.x, a.y), pk2(a.z, a.w), pk2(b2.x, b2.y), pk2(b2.z, b2.w)};
        *reinterpret_cast<uint4*>(EL + row * ESTR2 + iu * 8) =
            *reinterpret_cast<uint4*>(w);
      }
    }
    // ---- stage TL [256][32] ----
    #pragma unroll
    for (int p = 0; p < 4; ++p) {
      const int unit = tid + 256 * p;
      const int dr = unit >> 2, iu = unit & 3;
      *reinterpret_cast<uint4*>(TL + dr * TSTR2 + iu * 8) =
          *reinterpret_cast<const uint4*>(et + ((size_t)b * D_ + dr) * L_ + l0 + iu * 8);
    }
    __syncthreads();  // tiles ready

    // ---- QK^T (swapped): S^T[l][n], A=E rows, B=Q ----
    float sv[8];
    #pragma unroll
    for (int tt = 0; tt < 2; ++tt) {
      f32x4 sacc = (f32x4){0.f, 0.f, 0.f, 0.f};
      #pragma unroll
      for (int dk = 0; dk < 8; ++dk) {
        bf16x8 af = *reinterpret_cast<const bf16x8*>(EL + (16*tt + c) * ESTR2 + 32*dk + 8*g);
        sacc = __builtin_amdgcn_mfma_f32_16x16x32_bf16(af, qf[dk], sacc, 0, 0, 0);
      }
      #pragma unroll
      for (int r = 0; r < 4; ++r) {
        float v = sacc[r] * scale;
        if (mv[4*tt+r]) v = NEG_;
        sv[4*tt+r] = v;
      }
    }

    // ---- online softmax (lane owns n=c; rows l across tt,r in-lane, g cross-lane) ----
    float tm = sv[0];
    #pragma unroll
    for (int i = 1; i < 8; ++i) tm = fmaxf(tm, sv[i]);
    tm = fmaxf(tm, __shfl_xor(tm, 16));
    tm = fmaxf(tm, __shfl_xor(tm, 32));
    const float m_new = fmaxf(m_run, tm);
    const float alpha = __builtin_amdgcn_exp2f((m_run - m_new) * LOG2E_);
    float ts = 0.f;
    #pragma unroll
    for (int i = 0; i < 8; ++i) {
      sv[i] = __builtin_amdgcn_exp2f((sv[i] - m_new) * LOG2E_);
      ts += sv[i];
    }
    ts += __shfl_xor(ts, 16);
    ts += __shfl_xor(ts, 32);
    l_run = l_run * alpha + ts;
    m_run = m_new;

    float ar[4];
    #pragma unroll
    for (int r = 0; r < 4; ++r) ar[r] = __shfl(alpha, 4*g + r, 64);
    #pragma unroll
    for (int j = 0; j < 16; ++j)
      #pragma unroll
      for (int r = 0; r < 4; ++r) oacc[j][r] *= ar[r];

    // ---- P -> wave-private LDS, layout [n=c][l] ----
    #pragma unroll
    for (int tt = 0; tt < 2; ++tt) {
      uint2 w;
      w.x = pk2(sv[4*tt+0], sv[4*tt+1]);
      w.y = pk2(sv[4*tt+2], sv[4*tt+3]);
      *reinterpret_cast<uint2*>(PLw + c * PSTR2 + 16*tt + 4*g) = w;
    }

    // ---- PV: O[n][d] += P[n][l] * E[l][d]; A=P, B=E^T rows; K=32 = full tile ----
    bf16x8 pa = *reinterpret_cast<const bf16x8*>(PLw + c * PSTR2 + 8*g);
    #pragma unroll
    for (int j = 0; j < 16; ++j) {
      bf16x8 bfr = *reinterpret_cast<const bf16x8*>(TL + (16*j + c) * TSTR2 + 8*g);
      oacc[j] = __builtin_amdgcn_mfma_f32_16x16x32_bf16(pa, bfr, oacc[j], 0, 0, 0);
    }
  }

  // ---- write partials ----
  const size_t slot = (size_t)rest * 16 + nt;       // (b*S+s)*16+nt
  float* ob = opart + slot * (64 * 256);
  #pragma unroll
  for (int r = 0; r < 4; ++r) {
    const int row = wid * 16 + 4*g + r;
    #pragma unroll
    for (int j = 0; j < 16; ++j)
      ob[(size_t)row * 256 + 16*j + c] = oacc[j][r];
  }
  if (g == 0) {   // lanes 0..15 hold (m,l) for n-local = wid*16 + c
    mpart[slot * 64 + wid * 16 + c] = m_run;
    lpart[slot * 64 + wid * 16 + c] = l_run;
  }
}

// ---------------- phase 2: combine partials + residual LayerNorm ----------------
__global__ __launch_bounds__(256)
void combine_ln(const float* __restrict__ q, const float* __restrict__ gamma,
                const float* __restrict__ beta, const float* __restrict__ opart,
                const float* __restrict__ mpart, const float* __restrict__ lpart,
                int S, float* __restrict__ out) {
  const int tid = threadIdx.x, wid = tid >> 6, lane = tid & 63;
  const int row = blockIdx.x * 4 + wid;      // 0..16383
  const int b = row >> 10, n = row & 1023;
  const int nt = n >> 6, nl = n & 63;

  float M = -INFINITY;
  for (int s = 0; s < S; ++s) {
    const size_t slot = (size_t)(b * S + s) * 16 + nt;
    M = fmaxf(M, mpart[slot * 64 + nl]);
  }
  float Ls = 0.f;
  float4 o = make_float4(0.f, 0.f, 0.f, 0.f);
  for (int s = 0; s < S; ++s) {
    const size_t slot = (size_t)(b * S + s) * 16 + nt;
    const float w = __builtin_amdgcn_exp2f((mpart[slot * 64 + nl] - M) * LOG2E_);
    Ls += w * lpart[slot * 64 + nl];
    float4 os = *reinterpret_cast<const float4*>(
        opart + (slot * 64 + nl) * 256 + lane * 4);
    o.x += w * os.x; o.y += w * os.y; o.z += w * os.z; o.w += w * os.w;
  }
  const float invL = 1.f / Ls;
  float4 qv = *reinterpret_cast<const float4*>(q + ((size_t)b * N_ + n) * D_ + lane * 4);
  float4 x;
  x.x = qv.x + o.x * invL; x.y = qv.y + o.y * invL;
  x.z = qv.z + o.z * invL; x.w = qv.w + o.w * invL;

  float sum = x.x + x.y + x.z + x.w;
  sum += __shfl_xor(sum, 1);  sum += __shfl_xor(sum, 2);
  sum += __shfl_xor(sum, 4);  sum += __shfl_xor(sum, 8);
  sum += __shfl_xor(sum, 16); sum += __shfl_xor(sum, 32);
  const float mu = sum * (1.f / 256.f);
  float dx, v2 = 0.f;
  dx = x.x - mu; v2 += dx * dx; dx = x.y - mu; v2 += dx * dx;
  dx = x.z - mu; v2 += dx * dx; dx = x.w - mu; v2 += dx * dx;
  v2 += __shfl_xor(v2, 1);  v2 += __shfl_xor(v2, 2);
  v2 += __shfl_xor(v2, 4);  v2 += __shfl_xor(v2, 8);
  v2 += __shfl_xor(v2, 16); v2 += __shfl_xor(v2, 32);
  const float rs = rsqrtf(v2 * (1.f / 256.f) + EPS_);
  float4 gv = *reinterpret_cast<const float4*>(gamma + lane * 4);
  float4 bv = *reinterpret_cast<const float4*>(beta + lane * 4);
  float4 y;
  y.x = (x.x - mu) * rs * gv.x + bv.x;
  y.y = (x.y - mu) * rs * gv.y + bv.y;
  y.z = (x.z - mu) * rs * gv.z + bv.z;
  y.w = (x.w - mu) * rs * gv.w + bv.w;
  *reinterpret_cast<float4*>(out + ((size_t)b * N_ + n) * D_ + lane * 4) = y;
}

// ---------------- round-3 single-kernel path (middle tier, validated) ----------------
__global__ __launch_bounds__(256)
void attn_kernel(const float* __restrict__ ef, const float* __restrict__ q,
                 const int* __restrict__ msk, const float* __restrict__ gamma,
                 const float* __restrict__ beta, const __hip_bfloat16* __restrict__ et,
                 const __hip_bfloat16* __restrict__ ebf, int use_ebf,
                 float* __restrict__ out) {
  extern __shared__ char smem[];
  __hip_bfloat16* EL  = (__hip_bfloat16*)smem;
  __hip_bfloat16* TL  = EL + 64 * ESTR;
  __hip_bfloat16* PLb = TL + 256 * TSTR;
  const int tid  = threadIdx.x;
  const int wid  = tid >> 6, lane = tid & 63;
  const int g = lane >> 4, c = lane & 15;
  const int raw = blockIdx.x;
  const int bs  = (raw & 7) * 32 + (raw >> 3);
  const int b   = bs >> 4;
  const int n0w = (bs & 15) * 64 + wid * 16;
  bf16x8 qf[8];
  {
    const float* qrow = q + ((size_t)b * N_ + n0w + c) * D_;
    #pragma unroll
    for (int dk = 0; dk < 8; ++dk) {
      float4 a  = *reinterpret_cast<const float4*>(qrow + 32 * dk + 8 * g);
      float4 b2 = *reinterpret_cast<const float4*>(qrow + 32 * dk + 8 * g + 4);
      u32 w[4] = {pk2(a.x, a.y), pk2(a.z, a.w), pk2(b2.x, b2.y), pk2(b2.z, b2.w)};
      qf[dk] = *reinterpret_cast<bf16x8*>(w);
    }
  }
  f32x4 oacc[16];
  #pragma unroll
  for (int j = 0; j < 16; ++j) oacc[j] = (f32x4){0.f, 0.f, 0.f, 0.f};
  float m_run = -INFINITY, l_run = 0.f;
  __hip_bfloat16* PLw = PLb + wid * 16 * PSTR;
  for (int t64 = 0; t64 < L_ / 64; ++t64) {
    const int l0 = t64 * 64;
    int mv[16];
    #pragma unroll
    for (int t = 0; t < 4; ++t)
      #pragma unroll
      for (int r = 0; r < 4; ++r)
        mv[4*t+r] = msk[((size_t)b * L_ + l0 + 16*t + 4*g + r) * N_ + n0w + c];
    __syncthreads();
    {
      const int row = tid & 63, sg = tid >> 6;
      if (use_ebf) {
        const __hip_bfloat16* src = ebf + ((size_t)b * L_ + l0 + row) * D_ + sg * 64;
        #pragma unroll
        for (int p = 0; p < 8; ++p)
          *reinterpret_cast<uint4*>(EL + row * ESTR + sg * 64 + p * 8) =
              *reinterpret_cast<const uint4*>(src + p * 8);
      } else {
        const float* src = ef + ((size_t)b * L_ + l0 + row) * D_ + sg * 64;
        #pragma unroll
        for (int p = 0; p < 8; ++p) {
          float4 a  = *reinterpret_cast<const float4*>(src + p * 8);
          float4 b2 = *reinterpret_cast<const float4*>(src + p * 8 + 4);
          u32 w[4] = {pk2(a.x, a.y), pk2(a.z, a.w), pk2(b2.x, b2.y), pk2(b2.z, b2.w)};
          *reinterpret_cast<uint4*>(EL + row * ESTR + sg * 64 + p * 8) =
              *reinterpret_cast<uint4*>(w);
        }
      }
    }
    {
      const __hip_bfloat16* src = et + ((size_t)b * D_ + tid) * L_ + l0;
      #pragma unroll
      for (int p = 0; p < 8; ++p)
        *reinterpret_cast<uint4*>(TL + tid * TSTR + p * 8) =
            *reinterpret_cast<const uint4*>(src + p * 8);
    }
    __syncthreads();
    float sv[16];
    #pragma unroll
    for (int t = 0; t < 4; ++t) {
      f32x4 sacc = (f32x4){0.f, 0.f, 0.f, 0.f};
      #pragma unroll
      for (int dk = 0; dk < 8; ++dk) {
        bf16x8 af = *reinterpret_cast<const bf16x8*>(EL + (16*t + c) * ESTR + 32*dk + 8*g);
        sacc = __builtin_amdgcn_mfma_f32_16x16x32_bf16(af, qf[dk], sacc, 0, 0, 0);
      }
      #pragma unroll
      for (int r = 0; r < 4; ++r) {
        float v = sacc[r] * 0.0625f;
        if (mv[4*t+r]) v = NEG_;
        sv[4*t+r] = v;
      }
    }
    float tm = sv[0];
    #pragma unroll
    for (int i = 1; i < 16; ++i) tm = fmaxf(tm, sv[i]);
    tm = fmaxf(tm, __shfl_xor(tm, 16));
    tm = fmaxf(tm, __shfl_xor(tm, 32));
    const float m_new = fmaxf(m_run, tm);
    const float alpha = __builtin_amdgcn_exp2f((m_run - m_new) * LOG2E_);
    float ts = 0.f;
    #pragma unroll
    for (int i = 0; i < 16; ++i) {
      sv[i] = __builtin_amdgcn_exp2f((sv[i] - m_new) * LOG2E_);
      ts += sv[i];
    }
    ts += __shfl_xor(ts, 16);
    ts += __shfl_xor(ts, 32);
    l_run = l_run * alpha + ts;
    m_run = m_new;
    float ar[4];
    #pragma unroll
    for (int r = 0; r < 4; ++r) ar[r] = __shfl(alpha, 4*g + r, 64);
    #pragma unroll
    for (int j = 0; j < 16; ++j)
      #pragma unroll
      for (int r = 0; r < 4; ++r) oacc[j][r] *= ar[r];
    #pragma unroll
    for (int t = 0; t < 4; ++t) {
      uint2 w;
      w.x = pk2(sv[4*t+0], sv[4*t+1]);
      w.y = pk2(sv[4*t+2], sv[4*t+3]);
      *reinterpret_cast<uint2*>(PLw + c * PSTR + 16*t + 4*g) = w;
    }
    #pragma unroll
    for (int h = 0; h < 2; ++h) {
      bf16x8 pa = *reinterpret_cast<const bf16x8*>(PLw + c * PSTR + 32*h + 8*g);
      #pragma unroll
      for (int j = 0; j < 16; ++j) {
        bf16x8 bfr = *reinterpret_cast<const bf16x8*>(TL + (16*j + c) * TSTR + 32*h + 8*g);
        oacc[j] = __builtin_amdgcn_mfma_f32_16x16x32_bf16(pa, bfr, oacc[j], 0, 0, 0);
      }
    }
  }
  float invl[4];
  #pragma unroll
  for (int r = 0; r < 4; ++r) invl[r] = 1.f / __shfl(l_run, 4*g + r, 64);
  float gv[16], bv[16];
  #pragma unroll
  for (int j = 0; j < 16; ++j) { gv[j] = gamma[16*j + c]; bv[j] = beta[16*j + c]; }
  const float* qb = q + ((size_t)b * N_ + n0w) * D_;
  float* ob = out + ((size_t)b * N_ + n0w) * D_;
  #pragma unroll
  for (int r = 0; r < 4; ++r) {
    const int n = 4*g + r;
    float x[16], s = 0.f;
    #pragma unroll
    for (int j = 0; j < 16; ++j) {
      x[j] = qb[(size_t)n * D_ + 16*j + c] + oacc[j][r] * invl[r];
      s += x[j];
    }
    s += __shfl_xor(s, 1); s += __shfl_xor(s, 2);
    s += __shfl_xor(s, 4); s += __shfl_xor(s, 8);
    const float mu = s * (1.f / 256.f);
    float v2 = 0.f;
    #pragma unroll
    for (int j = 0; j < 16; ++j) { float d = x[j] - mu; v2 += d * d; }
    v2 += __shfl_xor(v2, 1); v2 += __shfl_xor(v2, 2);
    v2 += __shfl_xor(v2, 4); v2 += __shfl_xor(v2, 8);
    const float rs = rsqrtf(v2 * (1.f / 256.f) + EPS_);
    #pragma unroll
    for (int j = 0; j < 16; ++j)
      ob[(size_t)n * D_ + 16*j + c] = (x[j] - mu) * rs * gv[j] + bv[j];
  }
}

// ---------------- f32 fallback (round-2 proven) ----------------
#define QSTRIDE (D_ + 4)
#define PSTRIDF (64 + 4)
__global__ __launch_bounds__(256)
void tgq_fallback(const float* __restrict__ ef, const float* __restrict__ q,
                  const int* __restrict__ msk, const float* __restrict__ gamma,
                  const float* __restrict__ beta, float* __restrict__ out) {
  extern __shared__ float fsm[];
  float* QL = fsm;
  float* EL = QL + 64 * QSTRIDE;
  float* PL = EL + 64 * QSTRIDE;
  const int tid = threadIdx.x, tx = tid & 15, ty = tid >> 4;
  const int b = blockIdx.x >> 4, n0 = (blockIdx.x & 15) * 64;
  {
    const float* qsrc = q + ((size_t)b * N_ + n0) * D_;
    for (int idx = tid; idx < 64 * 64; idx += 256) {
      int row = idx >> 6, c4 = idx & 63;
      *reinterpret_cast<float4*>(&QL[row * QSTRIDE + c4 * 4]) =
          *reinterpret_cast<const float4*>(qsrc + (size_t)row * D_ + c4 * 4);
    }
  }
  float4 O4[4][4]; float m_run[4], l_run[4];
  #pragma unroll
  for (int i = 0; i < 4; ++i) {
    m_run[i] = -INFINITY; l_run[i] = 0.f;
    #pragma unroll
    for (int k = 0; k < 4; ++k) O4[i][k] = make_float4(0.f, 0.f, 0.f, 0.f);
  }
  const float* efb = ef + (size_t)b * L_ * D_;
  const int* mb = msk + (size_t)b * L_ * N_;
  for (int t = 0; t < L_ / 64; ++t) {
    const int l0 = t * 64;
    __syncthreads();
    for (int idx = tid; idx < 64 * 64; idx += 256) {
      int row = idx >> 6, c4 = idx & 63;
      *reinterpret_cast<float4*>(&EL[row * QSTRIDE + c4 * 4]) =
          *reinterpret_cast<const float4*>(efb + (size_t)(l0 + row) * D_ + c4 * 4);
    }
    int4 mvv[4];
    #pragma unroll
    for (int j = 0; j < 4; ++j)
      mvv[j] = *reinterpret_cast<const int4*>(mb + (size_t)(l0 + tx + 16*j) * N_ + n0 + 4*ty);
    __syncthreads();
    float s0[4][4];
    #pragma unroll
    for (int i = 0; i < 4; ++i)
      #pragma unroll
      for (int j = 0; j < 4; ++j) s0[i][j] = 0.f;
    #pragma unroll 4
    for (int dq = 0; dq < 64; ++dq) {
      float4 qv[4], ev[4];
      #pragma unroll
      for (int i = 0; i < 4; ++i)
        qv[i] = *reinterpret_cast<const float4*>(&QL[(4*ty+i) * QSTRIDE + dq*4]);
      #pragma unroll
      for (int j = 0; j < 4; ++j)
        ev[j] = *reinterpret_cast<const float4*>(&EL[(tx+16*j) * QSTRIDE + dq*4]);
      #pragma unroll
      for (int i = 0; i < 4; ++i)
        #pragma unroll
        for (int j = 0; j < 4; ++j)
          s0[i][j] += qv[i].x*ev[j].x + qv[i].y*ev[j].y + qv[i].z*ev[j].z + qv[i].w*ev[j].w;
    }
    #pragma unroll
    for (int i = 0; i < 4; ++i)
      #pragma unroll
      for (int j = 0; j < 4; ++j) {
        float v = s0[i][j] * 0.0625f;
        int mi = (i==0)?mvv[j].x:(i==1)?mvv[j].y:(i==2)?mvv[j].z:mvv[j].w;
        if (mi) v = NEG_;
        s0[i][j] = v;
      }
    #pragma unroll
    for (int i = 0; i < 4; ++i) {
      float mt = fmaxf(fmaxf(s0[i][0], s0[i][1]), fmaxf(s0[i][2], s0[i][3]));
      mt = fmaxf(mt, __shfl_xor(mt,1)); mt = fmaxf(mt, __shfl_xor(mt,2));
      mt = fmaxf(mt, __shfl_xor(mt,4)); mt = fmaxf(mt, __shfl_xor(mt,8));
      float mn = fmaxf(m_run[i], mt);
      float alpha = __builtin_amdgcn_exp2f((m_run[i] - mn) * LOG2E_);
      float tsum = 0.f;
      #pragma unroll
      for (int j = 0; j < 4; ++j) {
        float p = __builtin_amdgcn_exp2f((s0[i][j] - mn) * LOG2E_);
        s0[i][j] = p; tsum += p;
      }
      tsum += __shfl_xor(tsum,1); tsum += __shfl_xor(tsum,2);
      tsum += __shfl_xor(tsum,4); tsum += __shfl_xor(tsum,8);
      l_run[i] = l_run[i] * alpha + tsum; m_run[i] = mn;
      #pragma unroll
      for (int k = 0; k < 4; ++k) {
        O4[i][k].x *= alpha; O4[i][k].y *= alpha; O4[i][k].z *= alpha; O4[i][k].w *= alpha;
      }
    }
    #pragma unroll
    for (int i = 0; i < 4; ++i)
      #pragma unroll
      for (int j = 0; j < 4; ++j)
        PL[(4*ty+i) * PSTRIDF + tx + 16*j] = s0[i][j];
    __syncthreads();
    #pragma unroll 2
    for (int l4 = 0; l4 < 16; ++l4) {
      float4 p4[4];
      #pragma unroll
      for (int i = 0; i < 4; ++i)
        p4[i] = *reinterpret_cast<const float4*>(&PL[(4*ty+i) * PSTRIDF + 4*l4]);
      #pragma unroll
      for (int cc = 0; cc < 4; ++cc) {
        float4 e4[4];
        #pragma unroll
        for (int k = 0; k < 4; ++k)
          e4[k] = *reinterpret_cast<const float4*>(&EL[(4*l4+cc) * QSTRIDE + 4*tx + 64*k]);
        #pragma unroll
        for (int i = 0; i < 4; ++i) {
          float pc = (cc==0)?p4[i].x:(cc==1)?p4[i].y:(cc==2)?p4[i].z:p4[i].w;
          #pragma unroll
          for (int k = 0; k < 4; ++k) {
            O4[i][k].x += pc*e4[k].x; O4[i][k].y += pc*e4[k].y;
            O4[i][k].z += pc*e4[k].z; O4[i][k].w += pc*e4[k].w;
          }
        }
      }
    }
  }
  float* outb = out + ((size_t)b * N_ + n0) * D_;
  #pragma unroll
  for (int i = 0; i < 4; ++i) {
    const int row = 4*ty + i;
    const float inv_l = 1.f / l_run[i];
    float4 xv[4]; float sum = 0.f;
    #pragma unroll
    for (int k = 0; k < 4; ++k) {
      const int d = 4*tx + 64*k;
      float4 qv = *reinterpret_cast<const float4*>(&QL[row * QSTRIDE + d]);
      xv[k].x = qv.x + O4[i][k].x*inv_l; xv[k].y = qv.y + O4[i][k].y*inv_l;
      xv[k].z = qv.z + O4[i][k].z*inv_l; xv[k].w = qv.w + O4[i][k].w*inv_l;
      sum += xv[k].x + xv[k].y + xv[k].z + xv[k].w;
    }
    sum += __shfl_xor(sum,1); sum += __shfl_xor(sum,2);
    sum += __shfl_xor(sum,4); sum += __shfl_xor(sum,8);
    const float mu = sum * (1.f / 256.f);
    float s2 = 0.f;
    #pragma unroll
    for (int k = 0; k < 4; ++k) {
      float dxx;
      dxx = xv[k].x-mu; s2 += dxx*dxx; dxx = xv[k].y-mu; s2 += dxx*dxx;
      dxx = xv[k].z-mu; s2 += dxx*dxx; dxx = xv[k].w-mu; s2 += dxx*dxx;
    }
    s2 += __shfl_xor(s2,1); s2 += __shfl_xor(s2,2);
    s2 += __shfl_xor(s2,4); s2 += __shfl_xor(s2,8);
    const float rs = rsqrtf(s2 * (1.f / 256.f) + EPS_);
    #pragma unroll
    for (int k = 0; k < 4; ++k) {
      const int d = 4*tx + 64*k;
      float4 gg = *reinterpret_cast<const float4*>(gamma + d);
      float4 be = *reinterpret_cast<const float4*>(beta + d);
      float4 y;
      y.x = (xv[k].x-mu)*rs*gg.x + be.x; y.y = (xv[k].y-mu)*rs*gg.y + be.y;
      y.z = (xv[k].z-mu)*rs*gg.z + be.z; y.w = (xv[k].w-mu)*rs*gg.w + be.w;
      *reinterpret_cast<float4*>(outb + (size_t)row * D_ + d) = y;
    }
  }
}

extern "C" void kernel_launch(void* const* d_in, const int* in_sizes, int n_in,
                              void* d_out, int out_size, void* d_ws, size_t ws_size,
                              hipStream_t stream) {
  const float* ef    = (const float*)d_in[0];
  const float* q     = (const float*)d_in[1];
  const int*   m     = (const int*)d_in[2];
  const float* gamma = (const float*)d_in[3];
  const float* beta  = (const float*)d_in[4];
  float* out         = (float*)d_out;

  const size_t et_b  = (size_t)B_ * D_ * L_ * 2;   // 33.55 MB
  const size_t ebf_b = (size_t)B_ * L_ * D_ * 2;   // 33.55 MB
  auto part_bytes = [](int S) {
    const size_t slots = (size_t)256 * S;
    return slots * 64 * 256 * 4 + 2 * slots * 64 * 4;
  };

  int slog = -1, use_ebf = 0;
  if      (ws_size >= et_b + ebf_b + part_bytes(8)) { slog = 3; use_ebf = 1; }
  else if (ws_size >= et_b + part_bytes(8))         { slog = 3; use_ebf = 0; }
  else if (ws_size >= et_b + ebf_b + part_bytes(4)) { slog = 2; use_ebf = 1; }
  else if (ws_size >= et_b + part_bytes(4))         { slog = 2; use_ebf = 0; }

  if (slog < 0) {
    if (ws_size >= et_b) {
      // round-3 single-kernel path
      use_ebf = (ws_size >= et_b + ebf_b) ? 1 : 0;
      __hip_bfloat16* et  = (__hip_bfloat16*)d_ws;
      __hip_bfloat16* ebf = use_ebf ? (et + (size_t)B_ * D_ * L_) : nullptr;
      prep_kernel<<<dim3(4096), dim3(256), 0, stream>>>(ef, et, ebf, use_ebf);
      const size_t lds3 = (size_t)(64 * ESTR + 256 * TSTR + 4 * 16 * PSTR) * 2;
      (void)hipFuncSetAttribute(reinterpret_cast<const void*>(attn_kernel),
                                hipFuncAttributeMaxDynamicSharedMemorySize, (int)lds3);
      attn_kernel<<<dim3(256), dim3(256), lds3, stream>>>(
          ef, q, m, gamma, beta, et, ebf, use_ebf, out);
    } else {
      const size_t lds = (size_t)(64*QSTRIDE + 64*QSTRIDE + 64*PSTRIDF) * sizeof(float);
      (void)hipFuncSetAttribute(reinterpret_cast<const void*>(tgq_fallback),
                                hipFuncAttributeMaxDynamicSharedMemorySize, (int)lds);
      tgq_fallback<<<dim3(256), dim3(256), lds, stream>>>(ef, q, m, gamma, beta, out);
    }
    return;
  }

  const int S = 1 << slog;
  __hip_bfloat16* et  = (__hip_bfloat16*)d_ws;
  __hip_bfloat16* ebf = use_ebf ? (et + (size_t)B_ * D_ * L_) : nullptr;
  float* opart = (float*)((char*)d_ws + et_b + (use_ebf ? ebf_b : 0));
  const size_t slots = (size_t)256 * S;
  float* mpart = opart + slots * 64 * 256;
  float* lpart = mpart + slots * 64;

  prep_kernel<<<dim3(4096), dim3(256), 0, stream>>>(ef, et, ebf, use_ebf);

  const size_t lds1 = (size_t)(LBLK * ESTR2 + 256 * TSTR2 + 4 * 16 * PSTR2) * 2;  // 42496
  attn_part<<<dim3(256 * S), dim3(256), lds1, stream>>>(
      ef, q, m, et, ebf, use_ebf, slog, opart, mpart, lpart);

  combine_ln<<<dim3(4096), dim3(256), 0, stream>>>(
      q, gamma, beta, opart, mpart, lpart, S, out);
}

// Round 5
// 315.322 us; speedup vs baseline: 4.8605x; 1.0877x over previous
//
#include <hip/hip_runtime.h>
#include <hip/hip_bf16.h>
#include <math.h>

typedef short bf16x8 __attribute__((ext_vector_type(8)));
typedef float f32x4 __attribute__((ext_vector_type(4)));
typedef unsigned int u32;
typedef unsigned short u16;

#define B_ 16
#define L_ 4096
#define N_ 1024
#define D_ 256
#define EPS_ 1e-5f
#define NEG_ -1.0e9f
#define LOG2E_ 1.4426950408889634f
#define THR_ 8.0f

#define LBLK 32
#define ESTR2 264   // EL row stride elems (528B; row-shift 4 words -> balanced b128)
#define TSTR2 40    // TL row stride elems (80B)
#define PSTR2 40

__device__ __forceinline__ u32 pk2(float x, float y) {
  __hip_bfloat16 hx = __float2bfloat16(x), hy = __float2bfloat16(y);
  return (u32)reinterpret_cast<unsigned short&>(hx) |
         ((u32)reinterpret_cast<unsigned short&>(hy) << 16);
}
__device__ __forceinline__ float bf2f(u16 u) {
  return __uint_as_float(((u32)u) << 16);
}

// ---------------- prep: f32 E -> bf16 E^T (+ optional bf16 E row-major) ----------------
__global__ __launch_bounds__(256)
void prep_kernel(const float* __restrict__ ef, __hip_bfloat16* __restrict__ et,
                 __hip_bfloat16* __restrict__ ebf, int write_ebf) {
  __shared__ float T[64][65];
  const int tid = threadIdx.x;
  const int bid = blockIdx.x;
  const int b  = bid >> 8;
  const int lt = (bid >> 2) & 63;
  const int dt = bid & 3;
  {
    const int r = tid & 63, s = tid >> 6;
    const float* src = ef + ((size_t)b * L_ + lt * 64 + r) * D_ + dt * 64 + s * 16;
    float v[16];
    #pragma unroll
    for (int k = 0; k < 4; ++k) {
      float4 f = *reinterpret_cast<const float4*>(src + 4 * k);
      v[4*k] = f.x; v[4*k+1] = f.y; v[4*k+2] = f.z; v[4*k+3] = f.w;
    }
    #pragma unroll
    for (int m = 0; m < 16; ++m) T[r][s * 16 + m] = v[m];
    if (write_ebf) {
      u32 w[8];
      #pragma unroll
      for (int p = 0; p < 8; ++p) w[p] = pk2(v[2*p], v[2*p+1]);
      __hip_bfloat16* dst = ebf + ((size_t)b * L_ + lt * 64 + r) * D_ + dt * 64 + s * 16;
      *reinterpret_cast<uint4*>(dst)     = *reinterpret_cast<uint4*>(&w[0]);
      *reinterpret_cast<uint4*>(dst + 8) = *reinterpret_cast<uint4*>(&w[4]);
    }
  }
  __syncthreads();
  {
    const int dcol = tid & 63, s2 = tid >> 6;
    float v[16];
    #pragma unroll
    for (int m = 0; m < 16; ++m) v[m] = T[s2 * 16 + m][dcol];
    u32 w[8];
    #pragma unroll
    for (int p = 0; p < 8; ++p) w[p] = pk2(v[2*p], v[2*p+1]);
    __hip_bfloat16* dst = et + ((size_t)b * D_ + dt * 64 + dcol) * L_ + lt * 64 + s2 * 16;
    *reinterpret_cast<uint4*>(dst)     = *reinterpret_cast<uint4*>(&w[0]);
    *reinterpret_cast<uint4*>(dst + 8) = *reinterpret_cast<uint4*>(&w[4]);
  }
}

// ---------------- phase 1: partial flash attention, 32 q per wave ----------------
// Block = (b, 128-query tile, L-split s); 4 waves x 32 q (two 16-col MFMA B-sets
// h=0,1 sharing every E/E^T fragment read). Defer-max rescale (T13, THR=8).
// Writes normalized bf16 O-partials + (m,l) f32 to workspace.
__global__ __launch_bounds__(256, 2)
void attn_part2(const float* __restrict__ ef, const float* __restrict__ q,
                const int* __restrict__ msk, const __hip_bfloat16* __restrict__ et,
                const __hip_bfloat16* __restrict__ ebf, int use_ebf, int slog,
                __hip_bfloat16* __restrict__ opart,
                float* __restrict__ mpart, float* __restrict__ lpart) {
  extern __shared__ char smem[];
  __hip_bfloat16* EL  = (__hip_bfloat16*)smem;     // [LBLK][ESTR2]
  __hip_bfloat16* TL  = EL + LBLK * ESTR2;         // [256][TSTR2]
  __hip_bfloat16* PLb = TL + 256 * TSTR2;          // [4][2][16][PSTR2]

  const int tid  = threadIdx.x;
  const int wid  = tid >> 6;
  const int lane = tid & 63;
  const int g    = lane >> 4;
  const int c    = lane & 15;

  const int S   = 1 << slog;
  const int nb  = 128 << slog;
  const int raw = blockIdx.x;
  const int cpx = nb >> 3;
  const int bs  = (raw & 7) * cpx + (raw >> 3);   // XCD-chunked swizzle
  const int nt   = bs & 7;
  const int rest = bs >> 3;                        // b*S + s
  const int s    = rest & (S - 1);
  const int b    = rest >> slog;

  const int lsplit = L_ >> slog;
  const int lbase  = s * lsplit;
  const int n0w    = nt * 128 + wid * 32;

  // ---- hoist Q fragments for both 16-col sets ----
  bf16x8 qf[2][8];
  #pragma unroll
  for (int h = 0; h < 2; ++h) {
    const float* qrow = q + ((size_t)b * N_ + n0w + 16*h + c) * D_;
    #pragma unroll
    for (int dk = 0; dk < 8; ++dk) {
      float4 a  = *reinterpret_cast<const float4*>(qrow + 32 * dk + 8 * g);
      float4 b2 = *reinterpret_cast<const float4*>(qrow + 32 * dk + 8 * g + 4);
      u32 w[4] = {pk2(a.x, a.y), pk2(a.z, a.w), pk2(b2.x, b2.y), pk2(b2.z, b2.w)};
      qf[h][dk] = *reinterpret_cast<bf16x8*>(w);
    }
  }

  f32x4 oacc[2][16];
  float m_run[2], l_run[2];
  #pragma unroll
  for (int h = 0; h < 2; ++h) {
    m_run[h] = -INFINITY; l_run[h] = 0.f;
    #pragma unroll
    for (int j = 0; j < 16; ++j) oacc[h][j] = (f32x4){0.f, 0.f, 0.f, 0.f};
  }

  __hip_bfloat16* PLw = PLb + wid * (2 * 16 * PSTR2);
  const float scale = 0.0625f;
  const int ntiles = lsplit / LBLK;

  for (int t = 0; t < ntiles; ++t) {
    const int l0 = lbase + t * LBLK;

    __syncthreads();  // previous tile fully consumed

    // ---- stage EL [32][256] (16B units) ----
    #pragma unroll
    for (int p = 0; p < 4; ++p) {
      const int unit = tid + 256 * p;
      const int row = unit >> 5, iu = unit & 31;
      if (use_ebf) {
        *reinterpret_cast<uint4*>(EL + row * ESTR2 + iu * 8) =
            *reinterpret_cast<const uint4*>(ebf + ((size_t)b * L_ + l0 + row) * D_ + iu * 8);
      } else {
        const float* src = ef + ((size_t)b * L_ + l0 + row) * D_ + iu * 8;
        float4 a  = *reinterpret_cast<const float4*>(src);
        float4 b2 = *reinterpret_cast<const float4*>(src + 4);
        u32 w[4] = {pk2(a.x, a.y), pk2(a.z, a.w), pk2(b2.x, b2.y), pk2(b2.z, b2.w)};
        *reinterpret_cast<uint4*>(EL + row * ESTR2 + iu * 8) =
            *reinterpret_cast<uint4*>(w);
      }
    }
    // ---- stage TL [256][32] ----
    #pragma unroll
    for (int p = 0; p < 4; ++p) {
      const int unit = tid + 256 * p;
      const int dr = unit >> 2, iu = unit & 3;
      *reinterpret_cast<uint4*>(TL + dr * TSTR2 + iu * 8) =
          *reinterpret_cast<const uint4*>(et + ((size_t)b * D_ + dr) * L_ + l0 + iu * 8);
    }

    // mask loads (overlap with staging latency)
    int mv[16];
    #pragma unroll
    for (int h = 0; h < 2; ++h)
      #pragma unroll
      for (int tt = 0; tt < 2; ++tt)
        #pragma unroll
        for (int r = 0; r < 4; ++r)
          mv[8*h + 4*tt + r] =
              msk[((size_t)b * L_ + l0 + 16*tt + 4*g + r) * N_ + n0w + 16*h + c];

    __syncthreads();  // tiles ready

    // ---- QK^T (swapped): each E fragment serves both h ----
    float sv[2][8];
    #pragma unroll
    for (int tt = 0; tt < 2; ++tt) {
      f32x4 s0 = (f32x4){0.f, 0.f, 0.f, 0.f};
      f32x4 s1 = (f32x4){0.f, 0.f, 0.f, 0.f};
      #pragma unroll
      for (int dk = 0; dk < 8; ++dk) {
        bf16x8 af = *reinterpret_cast<const bf16x8*>(EL + (16*tt + c) * ESTR2 + 32*dk + 8*g);
        s0 = __builtin_amdgcn_mfma_f32_16x16x32_bf16(af, qf[0][dk], s0, 0, 0, 0);
        s1 = __builtin_amdgcn_mfma_f32_16x16x32_bf16(af, qf[1][dk], s1, 0, 0, 0);
      }
      #pragma unroll
      for (int r = 0; r < 4; ++r) {
        float v0 = s0[r] * scale;
        float v1 = s1[r] * scale;
        if (mv[4*tt + r])     v0 = NEG_;
        if (mv[8 + 4*tt + r]) v1 = NEG_;
        sv[0][4*tt + r] = v0;
        sv[1][4*tt + r] = v1;
      }
    }

    // ---- per-h online softmax with defer-max + P write ----
    #pragma unroll
    for (int h = 0; h < 2; ++h) {
      float tm = sv[h][0];
      #pragma unroll
      for (int i = 1; i < 8; ++i) tm = fmaxf(tm, sv[h][i]);
      tm = fmaxf(tm, __shfl_xor(tm, 16));
      tm = fmaxf(tm, __shfl_xor(tm, 32));
      if (!__all(tm - m_run[h] <= THR_)) {       // wave-uniform branch
        const float mn = fmaxf(m_run[h], tm);
        const float alpha = __builtin_amdgcn_exp2f((m_run[h] - mn) * LOG2E_);
        l_run[h] *= alpha;
        float ar[4];
        #pragma unroll
        for (int r = 0; r < 4; ++r) ar[r] = __shfl(alpha, 4*g + r, 64);
        #pragma unroll
        for (int j = 0; j < 16; ++j)
          #pragma unroll
          for (int r = 0; r < 4; ++r) oacc[h][j][r] *= ar[r];
        m_run[h] = mn;
      }
      float ts = 0.f;
      #pragma unroll
      for (int i = 0; i < 8; ++i) {
        sv[h][i] = __builtin_amdgcn_exp2f((sv[h][i] - m_run[h]) * LOG2E_);
        ts += sv[h][i];
      }
      ts += __shfl_xor(ts, 16);
      ts += __shfl_xor(ts, 32);
      l_run[h] += ts;
      #pragma unroll
      for (int tt = 0; tt < 2; ++tt) {
        uint2 w;
        w.x = pk2(sv[h][4*tt+0], sv[h][4*tt+1]);
        w.y = pk2(sv[h][4*tt+2], sv[h][4*tt+3]);
        *reinterpret_cast<uint2*>(PLw + h * 16 * PSTR2 + c * PSTR2 + 16*tt + 4*g) = w;
      }
    }

    // ---- PV: each E^T fragment serves both h ----
    bf16x8 pa0 = *reinterpret_cast<const bf16x8*>(PLw + c * PSTR2 + 8*g);
    bf16x8 pa1 = *reinterpret_cast<const bf16x8*>(PLw + 16 * PSTR2 + c * PSTR2 + 8*g);
    #pragma unroll
    for (int j = 0; j < 16; ++j) {
      bf16x8 bfr = *reinterpret_cast<const bf16x8*>(TL + (16*j + c) * TSTR2 + 8*g);
      oacc[0][j] = __builtin_amdgcn_mfma_f32_16x16x32_bf16(pa0, bfr, oacc[0][j], 0, 0, 0);
      oacc[1][j] = __builtin_amdgcn_mfma_f32_16x16x32_bf16(pa1, bfr, oacc[1][j], 0, 0, 0);
    }
  }

  // ---- write normalized bf16 partials + (m,l) ----
  const size_t slot = (size_t)rest * 8 + nt;
  __hip_bfloat16* ob = opart + slot * (128 * 256);
  #pragma unroll
  for (int h = 0; h < 2; ++h) {
    float invl[4];
    #pragma unroll
    for (int r = 0; r < 4; ++r) invl[r] = 1.f / __shfl(l_run[h], 4*g + r, 64);
    #pragma unroll
    for (int r = 0; r < 4; ++r) {
      const int row = wid * 32 + 16*h + 4*g + r;
      #pragma unroll
      for (int j = 0; j < 16; ++j)
        ob[(size_t)row * 256 + 16*j + c] = __float2bfloat16(oacc[h][j][r] * invl[r]);
    }
  }
  if (g == 0) {
    #pragma unroll
    for (int h = 0; h < 2; ++h) {
      mpart[slot * 128 + wid * 32 + 16*h + c] = m_run[h];
      lpart[slot * 128 + wid * 32 + 16*h + c] = l_run[h];
    }
  }
}

// ---------------- phase 2: merge partials + residual LayerNorm ----------------
__global__ __launch_bounds__(256)
void combine_ln2(const float* __restrict__ q, const float* __restrict__ gamma,
                 const float* __restrict__ beta,
                 const __hip_bfloat16* __restrict__ opart,
                 const float* __restrict__ mpart, const float* __restrict__ lpart,
                 int S, float* __restrict__ out) {
  const int tid = threadIdx.x, wid = tid >> 6, lane = tid & 63;
  const int row = blockIdx.x * 4 + wid;     // 0..16383
  const int b = row >> 10, n = row & 1023;
  const int ntile = n >> 7, nl = n & 127;

  float M = -INFINITY;
  for (int s = 0; s < S; ++s) {
    const size_t slot = (size_t)(b * S + s) * 8 + ntile;
    M = fmaxf(M, mpart[slot * 128 + nl]);
  }
  float W = 0.f;
  float4 o = make_float4(0.f, 0.f, 0.f, 0.f);
  for (int s = 0; s < S; ++s) {
    const size_t slot = (size_t)(b * S + s) * 8 + ntile;
    const float w = __builtin_amdgcn_exp2f((mpart[slot * 128 + nl] - M) * LOG2E_) *
                    lpart[slot * 128 + nl];
    W += w;
    ushort4 ov = *reinterpret_cast<const ushort4*>(
        opart + (slot * 128 + nl) * 256 + lane * 4);
    o.x += w * bf2f(ov.x); o.y += w * bf2f(ov.y);
    o.z += w * bf2f(ov.z); o.w += w * bf2f(ov.w);
  }
  const float invW = 1.f / W;
  float4 qv = *reinterpret_cast<const float4*>(q + ((size_t)b * N_ + n) * D_ + lane * 4);
  float4 x;
  x.x = qv.x + o.x * invW; x.y = qv.y + o.y * invW;
  x.z = qv.z + o.z * invW; x.w = qv.w + o.w * invW;

  float sum = x.x + x.y + x.z + x.w;
  sum += __shfl_xor(sum, 1);  sum += __shfl_xor(sum, 2);
  sum += __shfl_xor(sum, 4);  sum += __shfl_xor(sum, 8);
  sum += __shfl_xor(sum, 16); sum += __shfl_xor(sum, 32);
  const float mu = sum * (1.f / 256.f);
  float dx, v2 = 0.f;
  dx = x.x - mu; v2 += dx * dx; dx = x.y - mu; v2 += dx * dx;
  dx = x.z - mu; v2 += dx * dx; dx = x.w - mu; v2 += dx * dx;
  v2 += __shfl_xor(v2, 1);  v2 += __shfl_xor(v2, 2);
  v2 += __shfl_xor(v2, 4);  v2 += __shfl_xor(v2, 8);
  v2 += __shfl_xor(v2, 16); v2 += __shfl_xor(v2, 32);
  const float rs = rsqrtf(v2 * (1.f / 256.f) + EPS_);
  float4 gv = *reinterpret_cast<const float4*>(gamma + lane * 4);
  float4 bv = *reinterpret_cast<const float4*>(beta + lane * 4);
  float4 y;
  y.x = (x.x - mu) * rs * gv.x + bv.x;
  y.y = (x.y - mu) * rs * gv.y + bv.y;
  y.z = (x.z - mu) * rs * gv.z + bv.z;
  y.w = (x.w - mu) * rs * gv.w + bv.w;
  *reinterpret_cast<float4*>(out + ((size_t)b * N_ + n) * D_ + lane * 4) = y;
}

// ---------------- f32 fallback (round-2 proven) ----------------
#define QSTRIDE (D_ + 4)
#define PSTRIDF (64 + 4)
__global__ __launch_bounds__(256)
void tgq_fallback(const float* __restrict__ ef, const float* __restrict__ q,
                  const int* __restrict__ msk, const float* __restrict__ gamma,
                  const float* __restrict__ beta, float* __restrict__ out) {
  extern __shared__ float fsm[];
  float* QL = fsm;
  float* EL = QL + 64 * QSTRIDE;
  float* PL = EL + 64 * QSTRIDE;
  const int tid = threadIdx.x, tx = tid & 15, ty = tid >> 4;
  const int b = blockIdx.x >> 4, n0 = (blockIdx.x & 15) * 64;
  {
    const float* qsrc = q + ((size_t)b * N_ + n0) * D_;
    for (int idx = tid; idx < 64 * 64; idx += 256) {
      int row = idx >> 6, c4 = idx & 63;
      *reinterpret_cast<float4*>(&QL[row * QSTRIDE + c4 * 4]) =
          *reinterpret_cast<const float4*>(qsrc + (size_t)row * D_ + c4 * 4);
    }
  }
  float4 O4[4][4]; float m_run[4], l_run[4];
  #pragma unroll
  for (int i = 0; i < 4; ++i) {
    m_run[i] = -INFINITY; l_run[i] = 0.f;
    #pragma unroll
    for (int k = 0; k < 4; ++k) O4[i][k] = make_float4(0.f, 0.f, 0.f, 0.f);
  }
  const float* efb = ef + (size_t)b * L_ * D_;
  const int* mb = msk + (size_t)b * L_ * N_;
  for (int t = 0; t < L_ / 64; ++t) {
    const int l0 = t * 64;
    __syncthreads();
    for (int idx = tid; idx < 64 * 64; idx += 256) {
      int row = idx >> 6, c4 = idx & 63;
      *reinterpret_cast<float4*>(&EL[row * QSTRIDE + c4 * 4]) =
          *reinterpret_cast<const float4*>(efb + (size_t)(l0 + row) * D_ + c4 * 4);
    }
    int4 mvv[4];
    #pragma unroll
    for (int j = 0; j < 4; ++j)
      mvv[j] = *reinterpret_cast<const int4*>(mb + (size_t)(l0 + tx + 16*j) * N_ + n0 + 4*ty);
    __syncthreads();
    float s0[4][4];
    #pragma unroll
    for (int i = 0; i < 4; ++i)
      #pragma unroll
      for (int j = 0; j < 4; ++j) s0[i][j] = 0.f;
    #pragma unroll 4
    for (int dq = 0; dq < 64; ++dq) {
      float4 qv[4], ev[4];
      #pragma unroll
      for (int i = 0; i < 4; ++i)
        qv[i] = *reinterpret_cast<const float4*>(&QL[(4*ty+i) * QSTRIDE + dq*4]);
      #pragma unroll
      for (int j = 0; j < 4; ++j)
        ev[j] = *reinterpret_cast<const float4*>(&EL[(tx+16*j) * QSTRIDE + dq*4]);
      #pragma unroll
      for (int i = 0; i < 4; ++i)
        #pragma unroll
        for (int j = 0; j < 4; ++j)
          s0[i][j] += qv[i].x*ev[j].x + qv[i].y*ev[j].y + qv[i].z*ev[j].z + qv[i].w*ev[j].w;
    }
    #pragma unroll
    for (int i = 0; i < 4; ++i)
      #pragma unroll
      for (int j = 0; j < 4; ++j) {
        float v = s0[i][j] * 0.0625f;
        int mi = (i==0)?mvv[j].x:(i==1)?mvv[j].y:(i==2)?mvv[j].z:mvv[j].w;
        if (mi) v = NEG_;
        s0[i][j] = v;
      }
    #pragma unroll
    for (int i = 0; i < 4; ++i) {
      float mt = fmaxf(fmaxf(s0[i][0], s0[i][1]), fmaxf(s0[i][2], s0[i][3]));
      mt = fmaxf(mt, __shfl_xor(mt,1)); mt = fmaxf(mt, __shfl_xor(mt,2));
      mt = fmaxf(mt, __shfl_xor(mt,4)); mt = fmaxf(mt, __shfl_xor(mt,8));
      float mn = fmaxf(m_run[i], mt);
      float alpha = __builtin_amdgcn_exp2f((m_run[i] - mn) * LOG2E_);
      float tsum = 0.f;
      #pragma unroll
      for (int j = 0; j < 4; ++j) {
        float p = __builtin_amdgcn_exp2f((s0[i][j] - mn) * LOG2E_);
        s0[i][j] = p; tsum += p;
      }
      tsum += __shfl_xor(tsum,1); tsum += __shfl_xor(tsum,2);
      tsum += __shfl_xor(tsum,4); tsum += __shfl_xor(tsum,8);
      l_run[i] = l_run[i] * alpha + tsum; m_run[i] = mn;
      #pragma unroll
      for (int k = 0; k < 4; ++k) {
        O4[i][k].x *= alpha; O4[i][k].y *= alpha; O4[i][k].z *= alpha; O4[i][k].w *= alpha;
      }
    }
    #pragma unroll
    for (int i = 0; i < 4; ++i)
      #pragma unroll
      for (int j = 0; j < 4; ++j)
        PL[(4*ty+i) * PSTRIDF + tx + 16*j] = s0[i][j];
    __syncthreads();
    #pragma unroll 2
    for (int l4 = 0; l4 < 16; ++l4) {
      float4 p4[4];
      #pragma unroll
      for (int i = 0; i < 4; ++i)
        p4[i] = *reinterpret_cast<const float4*>(&PL[(4*ty+i) * PSTRIDF + 4*l4]);
      #pragma unroll
      for (int cc = 0; cc < 4; ++cc) {
        float4 e4[4];
        #pragma unroll
        for (int k = 0; k < 4; ++k)
          e4[k] = *reinterpret_cast<const float4*>(&EL[(4*l4+cc) * QSTRIDE + 4*tx + 64*k]);
        #pragma unroll
        for (int i = 0; i < 4; ++i) {
          float pc = (cc==0)?p4[i].x:(cc==1)?p4[i].y:(cc==2)?p4[i].z:p4[i].w;
          #pragma unroll
          for (int k = 0; k < 4; ++k) {
            O4[i][k].x += pc*e4[k].x; O4[i][k].y += pc*e4[k].y;
            O4[i][k].z += pc*e4[k].z; O4[i][k].w += pc*e4[k].w;
          }
        }
      }
    }
  }
  float* outb = out + ((size_t)b * N_ + n0) * D_;
  #pragma unroll
  for (int i = 0; i < 4; ++i) {
    const int row = 4*ty + i;
    const float inv_l = 1.f / l_run[i];
    float4 xv[4]; float sum = 0.f;
    #pragma unroll
    for (int k = 0; k < 4; ++k) {
      const int d = 4*tx + 64*k;
      float4 qv = *reinterpret_cast<const float4*>(&QL[row * QSTRIDE + d]);
      xv[k].x = qv.x + O4[i][k].x*inv_l; xv[k].y = qv.y + O4[i][k].y*inv_l;
      xv[k].z = qv.z + O4[i][k].z*inv_l; xv[k].w = qv.w + O4[i][k].w*inv_l;
      sum += xv[k].x + xv[k].y + xv[k].z + xv[k].w;
    }
    sum += __shfl_xor(sum,1); sum += __shfl_xor(sum,2);
    sum += __shfl_xor(sum,4); sum += __shfl_xor(sum,8);
    const float mu = sum * (1.f / 256.f);
    float s2 = 0.f;
    #pragma unroll
    for (int k = 0; k < 4; ++k) {
      float dxx;
      dxx = xv[k].x-mu; s2 += dxx*dxx; dxx = xv[k].y-mu; s2 += dxx*dxx;
      dxx = xv[k].z-mu; s2 += dxx*dxx; dxx = xv[k].w-mu; s2 += dxx*dxx;
    }
    s2 += __shfl_xor(s2,1); s2 += __shfl_xor(s2,2);
    s2 += __shfl_xor(s2,4); s2 += __shfl_xor(s2,8);
    const float rs = rsqrtf(s2 * (1.f / 256.f) + EPS_);
    #pragma unroll
    for (int k = 0; k < 4; ++k) {
      const int d = 4*tx + 64*k;
      float4 gg = *reinterpret_cast<const float4*>(gamma + d);
      float4 be = *reinterpret_cast<const float4*>(beta + d);
      float4 y;
      y.x = (xv[k].x-mu)*rs*gg.x + be.x; y.y = (xv[k].y-mu)*rs*gg.y + be.y;
      y.z = (xv[k].z-mu)*rs*gg.z + be.z; y.w = (xv[k].w-mu)*rs*gg.w + be.w;
      *reinterpret_cast<float4*>(outb + (size_t)row * D_ + d) = y;
    }
  }
}

extern "C" void kernel_launch(void* const* d_in, const int* in_sizes, int n_in,
                              void* d_out, int out_size, void* d_ws, size_t ws_size,
                              hipStream_t stream) {
  const float* ef    = (const float*)d_in[0];
  const float* q     = (const float*)d_in[1];
  const int*   m     = (const int*)d_in[2];
  const float* gamma = (const float*)d_in[3];
  const float* beta  = (const float*)d_in[4];
  float* out         = (float*)d_out;

  const size_t et_b  = (size_t)B_ * D_ * L_ * 2;   // 33.55 MB
  const size_t ebf_b = (size_t)B_ * L_ * D_ * 2;   // 33.55 MB
  auto part_bytes = [](int S) {
    const size_t slots = (size_t)B_ * S * 8;       // (b,s,ntile128)
    return slots * 128 * 256 * 2 + 2 * slots * 128 * 4;   // bf16 O + f32 m,l
  };

  int slog = -1, use_ebf = 0;
  if      (ws_size >= et_b + ebf_b + part_bytes(8)) { slog = 3; use_ebf = 1; }
  else if (ws_size >= et_b + part_bytes(8))         { slog = 3; use_ebf = 0; }
  else if (ws_size >= et_b + ebf_b + part_bytes(4)) { slog = 2; use_ebf = 1; }
  else if (ws_size >= et_b + part_bytes(4))         { slog = 2; use_ebf = 0; }

  if (slog < 0) {
    const size_t lds = (size_t)(64*QSTRIDE + 64*QSTRIDE + 64*PSTRIDF) * sizeof(float);
    (void)hipFuncSetAttribute(reinterpret_cast<const void*>(tgq_fallback),
                              hipFuncAttributeMaxDynamicSharedMemorySize, (int)lds);
    tgq_fallback<<<dim3(256), dim3(256), lds, stream>>>(ef, q, m, gamma, beta, out);
    return;
  }

  const int S = 1 << slog;
  __hip_bfloat16* et  = (__hip_bfloat16*)d_ws;
  __hip_bfloat16* ebf = use_ebf ? (et + (size_t)B_ * D_ * L_) : nullptr;
  const size_t slots = (size_t)B_ * S * 8;
  __hip_bfloat16* opart = (__hip_bfloat16*)((char*)d_ws + et_b + (use_ebf ? ebf_b : 0));
  float* mpart = (float*)(opart + slots * 128 * 256);
  float* lpart = mpart + slots * 128;

  prep_kernel<<<dim3(4096), dim3(256), 0, stream>>>(ef, et, ebf, use_ebf);

  const size_t lds1 =
      (size_t)(LBLK * ESTR2 + 256 * TSTR2 + 4 * 2 * 16 * PSTR2) * 2;   // 47616 B
  attn_part2<<<dim3(128 * S), dim3(256), lds1, stream>>>(
      ef, q, m, et, ebf, use_ebf, slog, opart, mpart, lpart);

  combine_ln2<<<dim3(4096), dim3(256), 0, stream>>>(
      q, gamma, beta, opart, mpart, lpart, S, out);
}

// Round 7
// 296.527 us; speedup vs baseline: 5.1686x; 1.0634x over previous
//
#include <hip/hip_runtime.h>
#include <hip/hip_bf16.h>
#include <math.h>

typedef short bf16x8 __attribute__((ext_vector_type(8)));
typedef float f32x4 __attribute__((ext_vector_type(4)));
typedef unsigned int u32;
typedef unsigned short u16;

#define B_ 16
#define L_ 4096
#define N_ 1024
#define D_ 256
#define EPS_ 1e-5f
#define NEG_ -1.0e9f
#define LOG2E_ 1.4426950408889634f
#define THR_ 8.0f

#define LBLK 32
#define PSTR2 40
// reg-staging fallback tile strides (round-5 validated)
#define ESTR2 264
#define TSTR2 40

__device__ __forceinline__ u32 pk2(float x, float y) {
  __hip_bfloat16 hx = __float2bfloat16(x), hy = __float2bfloat16(y);
  return (u32)reinterpret_cast<unsigned short&>(hx) |
         ((u32)reinterpret_cast<unsigned short&>(hy) << 16);
}
__device__ __forceinline__ float bf2f(u16 u) {
  return __uint_as_float(((u32)u) << 16);
}

// ---------------- prep: f32 E -> bf16 E^T + SWIZZLED bf16 E row-major ----------------
// ebf row r stores 16B-unit u at position u ^ (r&7): ebf[r][pos] = unit (pos^sw).
// The DMA then copies LINEARLY (rule #21: swizzle applied once on write side,
// once on read side); the QK ds_read applies the same XOR to recover unit j.
__global__ __launch_bounds__(256)
void prep_kernel(const float* __restrict__ ef, __hip_bfloat16* __restrict__ et,
                 __hip_bfloat16* __restrict__ ebf, int write_ebf) {
  __shared__ float T[64][65];
  const int tid = threadIdx.x;
  const int bid = blockIdx.x;
  const int b  = bid >> 8;
  const int lt = (bid >> 2) & 63;
  const int dt = bid & 3;
  {
    const int r = tid & 63, s = tid >> 6;
    const float* src = ef + ((size_t)b * L_ + lt * 64 + r) * D_ + dt * 64 + s * 16;
    float v[16];
    #pragma unroll
    for (int k = 0; k < 4; ++k) {
      float4 f = *reinterpret_cast<const float4*>(src + 4 * k);
      v[4*k] = f.x; v[4*k+1] = f.y; v[4*k+2] = f.z; v[4*k+3] = f.w;
    }
    #pragma unroll
    for (int m = 0; m < 16; ++m) T[r][s * 16 + m] = v[m];
    if (write_ebf) {
      u32 w[8];
      #pragma unroll
      for (int p = 0; p < 8; ++p) w[p] = pk2(v[2*p], v[2*p+1]);
      __hip_bfloat16* dstrow = ebf + ((size_t)b * L_ + lt * 64 + r) * D_;
      const int u0 = dt * 8 + s * 2;       // 16B-unit index of first 8 elems
      const int sw = r & 7;
      *reinterpret_cast<uint4*>(dstrow + (size_t)(u0 ^ sw) * 8)       = *reinterpret_cast<uint4*>(&w[0]);
      *reinterpret_cast<uint4*>(dstrow + (size_t)((u0 + 1) ^ sw) * 8) = *reinterpret_cast<uint4*>(&w[4]);
    }
  }
  __syncthreads();
  {
    const int dcol = tid & 63, s2 = tid >> 6;
    float v[16];
    #pragma unroll
    for (int m = 0; m < 16; ++m) v[m] = T[s2 * 16 + m][dcol];
    u32 w[8];
    #pragma unroll
    for (int p = 0; p < 8; ++p) w[p] = pk2(v[2*p], v[2*p+1]);
    __hip_bfloat16* dst = et + ((size_t)b * D_ + dt * 64 + dcol) * L_ + lt * 64 + s2 * 16;
    *reinterpret_cast<uint4*>(dst)     = *reinterpret_cast<uint4*>(&w[0]);
    *reinterpret_cast<uint4*>(dst + 8) = *reinterpret_cast<uint4*>(&w[4]);
  }
}

// ---------------- phase 1 (gll path): async-staged partial flash attention ----------------
// Block = (b, 128-q tile, L-split); 4 waves x 32 q. Staging via global_load_lds
// (width 16) into double-buffered unpadded EL[32][256]/TL[256][32]; one barrier
// per tile; DMA for tile t+1 issued during compute of tile t (T3-minimum).
__global__ __launch_bounds__(256)
void attn_part3(const float* __restrict__ q, const int* __restrict__ msk,
                const __hip_bfloat16* __restrict__ et,
                const __hip_bfloat16* __restrict__ ebf, int slog,
                __hip_bfloat16* __restrict__ opart,
                float* __restrict__ mpart, float* __restrict__ lpart) {
  extern __shared__ char smem[];
  __hip_bfloat16* ELb = (__hip_bfloat16*)smem;   // 2 x [32][256]
  __hip_bfloat16* TLb = ELb + 2 * 32 * 256;      // 2 x [256][32]
  __hip_bfloat16* PLb = TLb + 2 * 256 * 32;      // [4][2][16][PSTR2]

  const int tid  = threadIdx.x;
  const int wid  = tid >> 6;
  const int lane = tid & 63;
  const int g    = lane >> 4;
  const int c    = lane & 15;

  const int S   = 1 << slog;
  const int nb  = 128 << slog;
  const int raw = blockIdx.x;
  const int cpx = nb >> 3;
  const int bs  = (raw & 7) * cpx + (raw >> 3);   // XCD-chunked swizzle (nb%8==0)
  const int nt   = bs & 7;
  const int rest = bs >> 3;                        // b*S + s
  const int s    = rest & (S - 1);
  const int b    = rest >> slog;

  const int lsplit = L_ >> slog;
  const int lbase  = s * lsplit;
  const int n0w    = nt * 128 + wid * 32;
  const int ntiles = lsplit / LBLK;

  // ---- hoist Q fragments for both 16-col sets ----
  bf16x8 qf[2][8];
  #pragma unroll
  for (int h = 0; h < 2; ++h) {
    const float* qrow = q + ((size_t)b * N_ + n0w + 16*h + c) * D_;
    #pragma unroll
    for (int dk = 0; dk < 8; ++dk) {
      float4 a  = *reinterpret_cast<const float4*>(qrow + 32 * dk + 8 * g);
      float4 b2 = *reinterpret_cast<const float4*>(qrow + 32 * dk + 8 * g + 4);
      u32 w[4] = {pk2(a.x, a.y), pk2(a.z, a.w), pk2(b2.x, b2.y), pk2(b2.z, b2.w)};
      qf[h][dk] = *reinterpret_cast<bf16x8*>(w);
    }
  }

  f32x4 oacc[2][16];
  float m_run[2], l_run[2];
  #pragma unroll
  for (int h = 0; h < 2; ++h) {
    m_run[h] = -INFINITY; l_run[h] = 0.f;
    #pragma unroll
    for (int j = 0; j < 16; ++j) oacc[h][j] = (f32x4){0.f, 0.f, 0.f, 0.f};
  }

  __hip_bfloat16* PLw = PLb + wid * (2 * 16 * PSTR2);
  const float scale = 0.0625f;

  // async DMA stage of one 32-l tile into buffer bufi
  auto STAGE = [&](int tindex, int bufi) {
    const int l0 = lbase + tindex * LBLK;
    __hip_bfloat16* ELd = ELb + bufi * (32 * 256);
    __hip_bfloat16* TLd = TLb + bufi * (256 * 32);
    #pragma unroll
    for (int p = 0; p < 4; ++p) {
      // EL: unit u = (wid*4+p)*64 + lane ; row=u>>5, iu=u&31.
      // Source is LINEAR: ebf is already pre-swizzled in global memory
      // (ebf[row][iu] = unit iu^(row&7)); the QK read applies the same XOR.
      const int u   = (wid * 4 + p) * 64 + lane;
      const int row = u >> 5, iu = u & 31;
      const __hip_bfloat16* src =
          ebf + ((size_t)b * L_ + l0 + row) * D_ + (size_t)iu * 8;
      __builtin_amdgcn_global_load_lds(
          (const __attribute__((address_space(1))) void*)src,
          (__attribute__((address_space(3))) void*)(ELd + (size_t)(wid * 4 + p) * 512),
          16, 0, 0);
    }
    #pragma unroll
    for (int p = 0; p < 4; ++p) {
      // TL: unit u ; dr=u>>2, iu=u&3
      const int u  = (wid * 4 + p) * 64 + lane;
      const int dr = u >> 2, iu = u & 3;
      const __hip_bfloat16* src =
          et + ((size_t)b * D_ + dr) * L_ + l0 + iu * 8;
      __builtin_amdgcn_global_load_lds(
          (const __attribute__((address_space(1))) void*)src,
          (__attribute__((address_space(3))) void*)(TLd + (size_t)(wid * 4 + p) * 512),
          16, 0, 0);
    }
  };

  STAGE(0, 0);
  int cur = 0;

  for (int t = 0; t < ntiles; ++t) {
    // compiler emits s_waitcnt vmcnt(0) before s_barrier: tile t's DMA (issued
    // one compute-phase ago) completes here; all waves done reading buf cur^1.
    __syncthreads();
    if (t + 1 < ntiles) STAGE(t + 1, cur ^ 1);

    const int l0 = lbase + t * LBLK;
    const __hip_bfloat16* ELc = ELb + cur * (32 * 256);
    const __hip_bfloat16* TLc = TLb + cur * (256 * 32);

    // mask loads (latency overlaps the QK MFMA chain below)
    int mv[16];
    #pragma unroll
    for (int h = 0; h < 2; ++h)
      #pragma unroll
      for (int tt = 0; tt < 2; ++tt)
        #pragma unroll
        for (int r = 0; r < 4; ++r)
          mv[8*h + 4*tt + r] =
              msk[((size_t)b * L_ + l0 + 16*tt + 4*g + r) * N_ + n0w + 16*h + c];

    // ---- QK^T (swapped): A = EL rows (XOR-swizzled units), B = qf ----
    float sv[2][8];
    __builtin_amdgcn_s_setprio(1);
    #pragma unroll
    for (int tt = 0; tt < 2; ++tt) {
      f32x4 s0 = (f32x4){0.f, 0.f, 0.f, 0.f};
      f32x4 s1 = (f32x4){0.f, 0.f, 0.f, 0.f};
      const __hip_bfloat16* Erow = ELc + (16*tt + c) * 256;
      const int sw = c & 7;
      #pragma unroll
      for (int dk = 0; dk < 8; ++dk) {
        bf16x8 af = *reinterpret_cast<const bf16x8*>(Erow + (size_t)((4*dk + g) ^ sw) * 8);
        s0 = __builtin_amdgcn_mfma_f32_16x16x32_bf16(af, qf[0][dk], s0, 0, 0, 0);
        s1 = __builtin_amdgcn_mfma_f32_16x16x32_bf16(af, qf[1][dk], s1, 0, 0, 0);
      }
      #pragma unroll
      for (int r = 0; r < 4; ++r) {
        float v0 = s0[r] * scale;
        float v1 = s1[r] * scale;
        if (mv[4*tt + r])     v0 = NEG_;
        if (mv[8 + 4*tt + r]) v1 = NEG_;
        sv[0][4*tt + r] = v0;
        sv[1][4*tt + r] = v1;
      }
    }
    __builtin_amdgcn_s_setprio(0);

    // ---- per-h online softmax with defer-max + P bounce to LDS ----
    #pragma unroll
    for (int h = 0; h < 2; ++h) {
      float tm = sv[h][0];
      #pragma unroll
      for (int i = 1; i < 8; ++i) tm = fmaxf(tm, sv[h][i]);
      tm = fmaxf(tm, __shfl_xor(tm, 16));
      tm = fmaxf(tm, __shfl_xor(tm, 32));
      if (!__all(tm - m_run[h] <= THR_)) {       // wave-uniform branch
        const float mn = fmaxf(m_run[h], tm);
        const float alpha = __builtin_amdgcn_exp2f((m_run[h] - mn) * LOG2E_);
        l_run[h] *= alpha;
        float ar[4];
        #pragma unroll
        for (int r = 0; r < 4; ++r) ar[r] = __shfl(alpha, 4*g + r, 64);
        #pragma unroll
        for (int j = 0; j < 16; ++j)
          #pragma unroll
          for (int r = 0; r < 4; ++r) oacc[h][j][r] *= ar[r];
        m_run[h] = mn;
      }
      float ts = 0.f;
      #pragma unroll
      for (int i = 0; i < 8; ++i) {
        sv[h][i] = __builtin_amdgcn_exp2f((sv[h][i] - m_run[h]) * LOG2E_);
        ts += sv[h][i];
      }
      ts += __shfl_xor(ts, 16);
      ts += __shfl_xor(ts, 32);
      l_run[h] += ts;
      #pragma unroll
      for (int tt = 0; tt < 2; ++tt) {
        uint2 w;
        w.x = pk2(sv[h][4*tt+0], sv[h][4*tt+1]);
        w.y = pk2(sv[h][4*tt+2], sv[h][4*tt+3]);
        *reinterpret_cast<uint2*>(PLw + h * 16 * PSTR2 + c * PSTR2 + 16*tt + 4*g) = w;
      }
    }

    // ---- PV: A = P, B = E^T rows (each fragment serves both h) ----
    bf16x8 pa0 = *reinterpret_cast<const bf16x8*>(PLw + c * PSTR2 + 8*g);
    bf16x8 pa1 = *reinterpret_cast<const bf16x8*>(PLw + 16 * PSTR2 + c * PSTR2 + 8*g);
    __builtin_amdgcn_s_setprio(1);
    #pragma unroll
    for (int j = 0; j < 16; ++j) {
      bf16x8 bfr = *reinterpret_cast<const bf16x8*>(TLc + (16*j + c) * 32 + 8*g);
      oacc[0][j] = __builtin_amdgcn_mfma_f32_16x16x32_bf16(pa0, bfr, oacc[0][j], 0, 0, 0);
      oacc[1][j] = __builtin_amdgcn_mfma_f32_16x16x32_bf16(pa1, bfr, oacc[1][j], 0, 0, 0);
    }
    __builtin_amdgcn_s_setprio(0);

    cur ^= 1;
  }

  // ---- write normalized bf16 partials + (m,l) ----
  const size_t slot = (size_t)rest * 8 + nt;
  __hip_bfloat16* ob = opart + slot * (128 * 256);
  #pragma unroll
  for (int h = 0; h < 2; ++h) {
    float invl[4];
    #pragma unroll
    for (int r = 0; r < 4; ++r) invl[r] = 1.f / __shfl(l_run[h], 4*g + r, 64);
    #pragma unroll
    for (int r = 0; r < 4; ++r) {
      const int row = wid * 32 + 16*h + 4*g + r;
      #pragma unroll
      for (int j = 0; j < 16; ++j)
        ob[(size_t)row * 256 + 16*j + c] = __float2bfloat16(oacc[h][j][r] * invl[r]);
    }
  }
  if (g == 0) {
    #pragma unroll
    for (int h = 0; h < 2; ++h) {
      mpart[slot * 128 + wid * 32 + 16*h + c] = m_run[h];
      lpart[slot * 128 + wid * 32 + 16*h + c] = l_run[h];
    }
  }
}

// ---------------- phase 1 fallback (round-5 validated reg-staging) ----------------
__global__ __launch_bounds__(256, 2)
void attn_part2(const float* __restrict__ ef, const float* __restrict__ q,
                const int* __restrict__ msk, const __hip_bfloat16* __restrict__ et,
                int slog, __hip_bfloat16* __restrict__ opart,
                float* __restrict__ mpart, float* __restrict__ lpart) {
  extern __shared__ char smem[];
  __hip_bfloat16* EL  = (__hip_bfloat16*)smem;
  __hip_bfloat16* TL  = EL + LBLK * ESTR2;
  __hip_bfloat16* PLb = TL + 256 * TSTR2;
  const int tid  = threadIdx.x;
  const int wid  = tid >> 6;
  const int lane = tid & 63;
  const int g    = lane >> 4;
  const int c    = lane & 15;
  const int S   = 1 << slog;
  const int nb  = 128 << slog;
  const int raw = blockIdx.x;
  const int cpx = nb >> 3;
  const int bs  = (raw & 7) * cpx + (raw >> 3);
  const int nt   = bs & 7;
  const int rest = bs >> 3;
  const int s    = rest & (S - 1);
  const int b    = rest >> slog;
  const int lsplit = L_ >> slog;
  const int lbase  = s * lsplit;
  const int n0w    = nt * 128 + wid * 32;
  bf16x8 qf[2][8];
  #pragma unroll
  for (int h = 0; h < 2; ++h) {
    const float* qrow = q + ((size_t)b * N_ + n0w + 16*h + c) * D_;
    #pragma unroll
    for (int dk = 0; dk < 8; ++dk) {
      float4 a  = *reinterpret_cast<const float4*>(qrow + 32 * dk + 8 * g);
      float4 b2 = *reinterpret_cast<const float4*>(qrow + 32 * dk + 8 * g + 4);
      u32 w[4] = {pk2(a.x, a.y), pk2(a.z, a.w), pk2(b2.x, b2.y), pk2(b2.z, b2.w)};
      qf[h][dk] = *reinterpret_cast<bf16x8*>(w);
    }
  }
  f32x4 oacc[2][16];
  float m_run[2], l_run[2];
  #pragma unroll
  for (int h = 0; h < 2; ++h) {
    m_run[h] = -INFINITY; l_run[h] = 0.f;
    #pragma unroll
    for (int j = 0; j < 16; ++j) oacc[h][j] = (f32x4){0.f, 0.f, 0.f, 0.f};
  }
  __hip_bfloat16* PLw = PLb + wid * (2 * 16 * PSTR2);
  const float scale = 0.0625f;
  const int ntiles = lsplit / LBLK;
  for (int t = 0; t < ntiles; ++t) {
    const int l0 = lbase + t * LBLK;
    __syncthreads();
    #pragma unroll
    for (int p = 0; p < 4; ++p) {
      const int unit = tid + 256 * p;
      const int row = unit >> 5, iu = unit & 31;
      const float* src = ef + ((size_t)b * L_ + l0 + row) * D_ + iu * 8;
      float4 a  = *reinterpret_cast<const float4*>(src);
      float4 b2 = *reinterpret_cast<const float4*>(src + 4);
      u32 w[4] = {pk2(a.x, a.y), pk2(a.z, a.w), pk2(b2.x, b2.y), pk2(b2.z, b2.w)};
      *reinterpret_cast<uint4*>(EL + row * ESTR2 + iu * 8) = *reinterpret_cast<uint4*>(w);
    }
    #pragma unroll
    for (int p = 0; p < 4; ++p) {
      const int unit = tid + 256 * p;
      const int dr = unit >> 2, iu = unit & 3;
      *reinterpret_cast<uint4*>(TL + dr * TSTR2 + iu * 8) =
          *reinterpret_cast<const uint4*>(et + ((size_t)b * D_ + dr) * L_ + l0 + iu * 8);
    }
    int mv[16];
    #pragma unroll
    for (int h = 0; h < 2; ++h)
      #pragma unroll
      for (int tt = 0; tt < 2; ++tt)
        #pragma unroll
        for (int r = 0; r < 4; ++r)
          mv[8*h + 4*tt + r] =
              msk[((size_t)b * L_ + l0 + 16*tt + 4*g + r) * N_ + n0w + 16*h + c];
    __syncthreads();
    float sv[2][8];
    #pragma unroll
    for (int tt = 0; tt < 2; ++tt) {
      f32x4 s0 = (f32x4){0.f, 0.f, 0.f, 0.f};
      f32x4 s1 = (f32x4){0.f, 0.f, 0.f, 0.f};
      #pragma unroll
      for (int dk = 0; dk < 8; ++dk) {
        bf16x8 af = *reinterpret_cast<const bf16x8*>(EL + (16*tt + c) * ESTR2 + 32*dk + 8*g);
        s0 = __builtin_amdgcn_mfma_f32_16x16x32_bf16(af, qf[0][dk], s0, 0, 0, 0);
        s1 = __builtin_amdgcn_mfma_f32_16x16x32_bf16(af, qf[1][dk], s1, 0, 0, 0);
      }
      #pragma unroll
      for (int r = 0; r < 4; ++r) {
        float v0 = s0[r] * scale;
        float v1 = s1[r] * scale;
        if (mv[4*tt + r])     v0 = NEG_;
        if (mv[8 + 4*tt + r]) v1 = NEG_;
        sv[0][4*tt + r] = v0;
        sv[1][4*tt + r] = v1;
      }
    }
    #pragma unroll
    for (int h = 0; h < 2; ++h) {
      float tm = sv[h][0];
      #pragma unroll
      for (int i = 1; i < 8; ++i) tm = fmaxf(tm, sv[h][i]);
      tm = fmaxf(tm, __shfl_xor(tm, 16));
      tm = fmaxf(tm, __shfl_xor(tm, 32));
      if (!__all(tm - m_run[h] <= THR_)) {
        const float mn = fmaxf(m_run[h], tm);
        const float alpha = __builtin_amdgcn_exp2f((m_run[h] - mn) * LOG2E_);
        l_run[h] *= alpha;
        float ar[4];
        #pragma unroll
        for (int r = 0; r < 4; ++r) ar[r] = __shfl(alpha, 4*g + r, 64);
        #pragma unroll
        for (int j = 0; j < 16; ++j)
          #pragma unroll
          for (int r = 0; r < 4; ++r) oacc[h][j][r] *= ar[r];
        m_run[h] = mn;
      }
      float ts = 0.f;
      #pragma unroll
      for (int i = 0; i < 8; ++i) {
        sv[h][i] = __builtin_amdgcn_exp2f((sv[h][i] - m_run[h]) * LOG2E_);
        ts += sv[h][i];
      }
      ts += __shfl_xor(ts, 16);
      ts += __shfl_xor(ts, 32);
      l_run[h] += ts;
      #pragma unroll
      for (int tt = 0; tt < 2; ++tt) {
        uint2 w;
        w.x = pk2(sv[h][4*tt+0], sv[h][4*tt+1]);
        w.y = pk2(sv[h][4*tt+2], sv[h][4*tt+3]);
        *reinterpret_cast<uint2*>(PLw + h * 16 * PSTR2 + c * PSTR2 + 16*tt + 4*g) = w;
      }
    }
    bf16x8 pa0 = *reinterpret_cast<const bf16x8*>(PLw + c * PSTR2 + 8*g);
    bf16x8 pa1 = *reinterpret_cast<const bf16x8*>(PLw + 16 * PSTR2 + c * PSTR2 + 8*g);
    #pragma unroll
    for (int j = 0; j < 16; ++j) {
      bf16x8 bfr = *reinterpret_cast<const bf16x8*>(TL + (16*j + c) * TSTR2 + 8*g);
      oacc[0][j] = __builtin_amdgcn_mfma_f32_16x16x32_bf16(pa0, bfr, oacc[0][j], 0, 0, 0);
      oacc[1][j] = __builtin_amdgcn_mfma_f32_16x16x32_bf16(pa1, bfr, oacc[1][j], 0, 0, 0);
    }
  }
  const size_t slot = (size_t)rest * 8 + nt;
  __hip_bfloat16* ob = opart + slot * (128 * 256);
  #pragma unroll
  for (int h = 0; h < 2; ++h) {
    float invl[4];
    #pragma unroll
    for (int r = 0; r < 4; ++r) invl[r] = 1.f / __shfl(l_run[h], 4*g + r, 64);
    #pragma unroll
    for (int r = 0; r < 4; ++r) {
      const int row = wid * 32 + 16*h + 4*g + r;
      #pragma unroll
      for (int j = 0; j < 16; ++j)
        ob[(size_t)row * 256 + 16*j + c] = __float2bfloat16(oacc[h][j][r] * invl[r]);
    }
  }
  if (g == 0) {
    #pragma unroll
    for (int h = 0; h < 2; ++h) {
      mpart[slot * 128 + wid * 32 + 16*h + c] = m_run[h];
      lpart[slot * 128 + wid * 32 + 16*h + c] = l_run[h];
    }
  }
}

// ---------------- phase 2: merge partials + residual LayerNorm ----------------
__global__ __launch_bounds__(256)
void combine_ln2(const float* __restrict__ q, const float* __restrict__ gamma,
                 const float* __restrict__ beta,
                 const __hip_bfloat16* __restrict__ opart,
                 const float* __restrict__ mpart, const float* __restrict__ lpart,
                 int S, float* __restrict__ out) {
  const int tid = threadIdx.x, wid = tid >> 6, lane = tid & 63;
  const int row = blockIdx.x * 4 + wid;
  const int b = row >> 10, n = row & 1023;
  const int ntile = n >> 7, nl = n & 127;

  float M = -INFINITY;
  for (int s = 0; s < S; ++s) {
    const size_t slot = (size_t)(b * S + s) * 8 + ntile;
    M = fmaxf(M, mpart[slot * 128 + nl]);
  }
  float W = 0.f;
  float4 o = make_float4(0.f, 0.f, 0.f, 0.f);
  for (int s = 0; s < S; ++s) {
    const size_t slot = (size_t)(b * S + s) * 8 + ntile;
    const float w = __builtin_amdgcn_exp2f((mpart[slot * 128 + nl] - M) * LOG2E_) *
                    lpart[slot * 128 + nl];
    W += w;
    ushort4 ov = *reinterpret_cast<const ushort4*>(
        opart + (slot * 128 + nl) * 256 + lane * 4);
    o.x += w * bf2f(ov.x); o.y += w * bf2f(ov.y);
    o.z += w * bf2f(ov.z); o.w += w * bf2f(ov.w);
  }
  const float invW = 1.f / W;
  float4 qv = *reinterpret_cast<const float4*>(q + ((size_t)b * N_ + n) * D_ + lane * 4);
  float4 x;
  x.x = qv.x + o.x * invW; x.y = qv.y + o.y * invW;
  x.z = qv.z + o.z * invW; x.w = qv.w + o.w * invW;

  float sum = x.x + x.y + x.z + x.w;
  sum += __shfl_xor(sum, 1);  sum += __shfl_xor(sum, 2);
  sum += __shfl_xor(sum, 4);  sum += __shfl_xor(sum, 8);
  sum += __shfl_xor(sum, 16); sum += __shfl_xor(sum, 32);
  const float mu = sum * (1.f / 256.f);
  float dx, v2 = 0.f;
  dx = x.x - mu; v2 += dx * dx; dx = x.y - mu; v2 += dx * dx;
  dx = x.z - mu; v2 += dx * dx; dx = x.w - mu; v2 += dx * dx;
  v2 += __shfl_xor(v2, 1);  v2 += __shfl_xor(v2, 2);
  v2 += __shfl_xor(v2, 4);  v2 += __shfl_xor(v2, 8);
  v2 += __shfl_xor(v2, 16); v2 += __shfl_xor(v2, 32);
  const float rs = rsqrtf(v2 * (1.f / 256.f) + EPS_);
  float4 gv = *reinterpret_cast<const float4*>(gamma + lane * 4);
  float4 bv = *reinterpret_cast<const float4*>(beta + lane * 4);
  float4 y;
  y.x = (x.x - mu) * rs * gv.x + bv.x;
  y.y = (x.y - mu) * rs * gv.y + bv.y;
  y.z = (x.z - mu) * rs * gv.z + bv.z;
  y.w = (x.w - mu) * rs * gv.w + bv.w;
  *reinterpret_cast<float4*>(out + ((size_t)b * N_ + n) * D_ + lane * 4) = y;
}

// ---------------- f32 fallback (round-2 proven) ----------------
#define QSTRIDE (D_ + 4)
#define PSTRIDF (64 + 4)
__global__ __launch_bounds__(256)
void tgq_fallback(const float* __restrict__ ef, const float* __restrict__ q,
                  const int* __restrict__ msk, const float* __restrict__ gamma,
                  const float* __restrict__ beta, float* __restrict__ out) {
  extern __shared__ float fsm[];
  float* QL = fsm;
  float* EL = QL + 64 * QSTRIDE;
  float* PL = EL + 64 * QSTRIDE;
  const int tid = threadIdx.x, tx = tid & 15, ty = tid >> 4;
  const int b = blockIdx.x >> 4, n0 = (blockIdx.x & 15) * 64;
  {
    const float* qsrc = q + ((size_t)b * N_ + n0) * D_;
    for (int idx = tid; idx < 64 * 64; idx += 256) {
      int row = idx >> 6, c4 = idx & 63;
      *reinterpret_cast<float4*>(&QL[row * QSTRIDE + c4 * 4]) =
          *reinterpret_cast<const float4*>(qsrc + (size_t)row * D_ + c4 * 4);
    }
  }
  float4 O4[4][4]; float m_run[4], l_run[4];
  #pragma unroll
  for (int i = 0; i < 4; ++i) {
    m_run[i] = -INFINITY; l_run[i] = 0.f;
    #pragma unroll
    for (int k = 0; k < 4; ++k) O4[i][k] = make_float4(0.f, 0.f, 0.f, 0.f);
  }
  const float* efb = ef + (size_t)b * L_ * D_;
  const int* mb = msk + (size_t)b * L_ * N_;
  for (int t = 0; t < L_ / 64; ++t) {
    const int l0 = t * 64;
    __syncthreads();
    for (int idx = tid; idx < 64 * 64; idx += 256) {
      int row = idx >> 6, c4 = idx & 63;
      *reinterpret_cast<float4*>(&EL[row * QSTRIDE + c4 * 4]) =
          *reinterpret_cast<const float4*>(efb + (size_t)(l0 + row) * D_ + c4 * 4);
    }
    int4 mvv[4];
    #pragma unroll
    for (int j = 0; j < 4; ++j)
      mvv[j] = *reinterpret_cast<const int4*>(mb + (size_t)(l0 + tx + 16*j) * N_ + n0 + 4*ty);
    __syncthreads();
    float s0[4][4];
    #pragma unroll
    for (int i = 0; i < 4; ++i)
      #pragma unroll
      for (int j = 0; j < 4; ++j) s0[i][j] = 0.f;
    #pragma unroll 4
    for (int dq = 0; dq < 64; ++dq) {
      float4 qv[4], ev[4];
      #pragma unroll
      for (int i = 0; i < 4; ++i)
        qv[i] = *reinterpret_cast<const float4*>(&QL[(4*ty+i) * QSTRIDE + dq*4]);
      #pragma unroll
      for (int j = 0; j < 4; ++j)
        ev[j] = *reinterpret_cast<const float4*>(&EL[(tx+16*j) * QSTRIDE + dq*4]);
      #pragma unroll
      for (int i = 0; i < 4; ++i)
        #pragma unroll
        for (int j = 0; j < 4; ++j)
          s0[i][j] += qv[i].x*ev[j].x + qv[i].y*ev[j].y + qv[i].z*ev[j].z + qv[i].w*ev[j].w;
    }
    #pragma unroll
    for (int i = 0; i < 4; ++i)
      #pragma unroll
      for (int j = 0; j < 4; ++j) {
        float v = s0[i][j] * 0.0625f;
        int mi = (i==0)?mvv[j].x:(i==1)?mvv[j].y:(i==2)?mvv[j].z:mvv[j].w;
        if (mi) v = NEG_;
        s0[i][j] = v;
      }
    #pragma unroll
    for (int i = 0; i < 4; ++i) {
      float mt = fmaxf(fmaxf(s0[i][0], s0[i][1]), fmaxf(s0[i][2], s0[i][3]));
      mt = fmaxf(mt, __shfl_xor(mt,1)); mt = fmaxf(mt, __shfl_xor(mt,2));
      mt = fmaxf(mt, __shfl_xor(mt,4)); mt = fmaxf(mt, __shfl_xor(mt,8));
      float mn = fmaxf(m_run[i], mt);
      float alpha = __builtin_amdgcn_exp2f((m_run[i] - mn) * LOG2E_);
      float tsum = 0.f;
      #pragma unroll
      for (int j = 0; j < 4; ++j) {
        float p = __builtin_amdgcn_exp2f((s0[i][j] - mn) * LOG2E_);
        s0[i][j] = p; tsum += p;
      }
      tsum += __shfl_xor(tsum,1); tsum += __shfl_xor(tsum,2);
      tsum += __shfl_xor(tsum,4); tsum += __shfl_xor(tsum,8);
      l_run[i] = l_run[i] * alpha + tsum; m_run[i] = mn;
      #pragma unroll
      for (int k = 0; k < 4; ++k) {
        O4[i][k].x *= alpha; O4[i][k].y *= alpha; O4[i][k].z *= alpha; O4[i][k].w *= alpha;
      }
    }
    #pragma unroll
    for (int i = 0; i < 4; ++i)
      #pragma unroll
      for (int j = 0; j < 4; ++j)
        PL[(4*ty+i) * PSTRIDF + tx + 16*j] = s0[i][j];
    __syncthreads();
    #pragma unroll 2
    for (int l4 = 0; l4 < 16; ++l4) {
      float4 p4[4];
      #pragma unroll
      for (int i = 0; i < 4; ++i)
        p4[i] = *reinterpret_cast<const float4*>(&PL[(4*ty+i) * PSTRIDF + 4*l4]);
      #pragma unroll
      for (int cc = 0; cc < 4; ++cc) {
        float4 e4[4];
        #pragma unroll
        for (int k = 0; k < 4; ++k)
          e4[k] = *reinterpret_cast<const float4*>(&EL[(4*l4+cc) * QSTRIDE + 4*tx + 64*k]);
        #pragma unroll
        for (int i = 0; i < 4; ++i) {
          float pc = (cc==0)?p4[i].x:(cc==1)?p4[i].y:(cc==2)?p4[i].z:p4[i].w;
          #pragma unroll
          for (int k = 0; k < 4; ++k) {
            O4[i][k].x += pc*e4[k].x; O4[i][k].y += pc*e4[k].y;
            O4[i][k].z += pc*e4[k].z; O4[i][k].w += pc*e4[k].w;
          }
        }
      }
    }
  }
  float* outb = out + ((size_t)b * N_ + n0) * D_;
  #pragma unroll
  for (int i = 0; i < 4; ++i) {
    const int row = 4*ty + i;
    const float inv_l = 1.f / l_run[i];
    float4 xv[4]; float sum = 0.f;
    #pragma unroll
    for (int k = 0; k < 4; ++k) {
      const int d = 4*tx + 64*k;
      float4 qv = *reinterpret_cast<const float4*>(&QL[row * QSTRIDE + d]);
      xv[k].x = qv.x + O4[i][k].x*inv_l; xv[k].y = qv.y + O4[i][k].y*inv_l;
      xv[k].z = qv.z + O4[i][k].z*inv_l; xv[k].w = qv.w + O4[i][k].w*inv_l;
      sum += xv[k].x + xv[k].y + xv[k].z + xv[k].w;
    }
    sum += __shfl_xor(sum,1); sum += __shfl_xor(sum,2);
    sum += __shfl_xor(sum,4); sum += __shfl_xor(sum,8);
    const float mu = sum * (1.f / 256.f);
    float s2 = 0.f;
    #pragma unroll
    for (int k = 0; k < 4; ++k) {
      float dxx;
      dxx = xv[k].x-mu; s2 += dxx*dxx; dxx = xv[k].y-mu; s2 += dxx*dxx;
      dxx = xv[k].z-mu; s2 += dxx*dxx; dxx = xv[k].w-mu; s2 += dxx*dxx;
    }
    s2 += __shfl_xor(s2,1); s2 += __shfl_xor(s2,2);
    s2 += __shfl_xor(s2,4); s2 += __shfl_xor(s2,8);
    const float rs = rsqrtf(s2 * (1.f / 256.f) + EPS_);
    #pragma unroll
    for (int k = 0; k < 4; ++k) {
      const int d = 4*tx + 64*k;
      float4 gg = *reinterpret_cast<const float4*>(gamma + d);
      float4 be = *reinterpret_cast<const float4*>(beta + d);
      float4 y;
      y.x = (xv[k].x-mu)*rs*gg.x + be.x; y.y = (xv[k].y-mu)*rs*gg.y + be.y;
      y.z = (xv[k].z-mu)*rs*gg.z + be.z; y.w = (xv[k].w-mu)*rs*gg.w + be.w;
      *reinterpret_cast<float4*>(outb + (size_t)row * D_ + d) = y;
    }
  }
}

extern "C" void kernel_launch(void* const* d_in, const int* in_sizes, int n_in,
                              void* d_out, int out_size, void* d_ws, size_t ws_size,
                              hipStream_t stream) {
  const float* ef    = (const float*)d_in[0];
  const float* q     = (const float*)d_in[1];
  const int*   m     = (const int*)d_in[2];
  const float* gamma = (const float*)d_in[3];
  const float* beta  = (const float*)d_in[4];
  float* out         = (float*)d_out;

  const size_t et_b  = (size_t)B_ * D_ * L_ * 2;   // 33.55 MB
  const size_t ebf_b = (size_t)B_ * L_ * D_ * 2;   // 33.55 MB
  auto part_bytes = [](int S) {
    const size_t slots = (size_t)B_ * S * 8;
    return slots * 128 * 256 * 2 + 2 * slots * 128 * 4;
  };

  // tier selection: gll path needs et + swizzled ebf + partials
  int slog = -1, use_gll = 0;
  if      (ws_size >= et_b + ebf_b + part_bytes(8)) { slog = 3; use_gll = 1; }
  else if (ws_size >= et_b + ebf_b + part_bytes(4)) { slog = 2; use_gll = 1; }
  else if (ws_size >= et_b + part_bytes(8))         { slog = 3; use_gll = 0; }
  else if (ws_size >= et_b + part_bytes(4))         { slog = 2; use_gll = 0; }

  if (slog < 0) {
    const size_t lds = (size_t)(64*QSTRIDE + 64*QSTRIDE + 64*PSTRIDF) * sizeof(float);
    (void)hipFuncSetAttribute(reinterpret_cast<const void*>(tgq_fallback),
                              hipFuncAttributeMaxDynamicSharedMemorySize, (int)lds);
    tgq_fallback<<<dim3(256), dim3(256), lds, stream>>>(ef, q, m, gamma, beta, out);
    return;
  }

  const int S = 1 << slog;
  __hip_bfloat16* et  = (__hip_bfloat16*)d_ws;
  __hip_bfloat16* ebf = use_gll ? (et + (size_t)B_ * D_ * L_) : nullptr;
  const size_t slots = (size_t)B_ * S * 8;
  __hip_bfloat16* opart =
      (__hip_bfloat16*)((char*)d_ws + et_b + (use_gll ? ebf_b : 0));
  float* mpart = (float*)(opart + slots * 128 * 256);
  float* lpart = mpart + slots * 128;

  prep_kernel<<<dim3(4096), dim3(256), 0, stream>>>(ef, et, ebf, use_gll);

  if (use_gll) {
    const size_t lds1 = (size_t)(2 * 32 * 256 + 2 * 256 * 32 + 4 * 2 * 16 * PSTR2) * 2;  // 75776
    (void)hipFuncSetAttribute(reinterpret_cast<const void*>(attn_part3),
                              hipFuncAttributeMaxDynamicSharedMemorySize, (int)lds1);
    attn_part3<<<dim3(128 * S), dim3(256), lds1, stream>>>(
        q, m, et, ebf, slog, opart, mpart, lpart);
  } else {
    const size_t lds1 = (size_t)(LBLK * ESTR2 + 256 * TSTR2 + 4 * 2 * 16 * PSTR2) * 2;
    attn_part2<<<dim3(128 * S), dim3(256), lds1, stream>>>(
        ef, q, m, et, slog, opart, mpart, lpart);
  }

  combine_ln2<<<dim3(4096), dim3(256), 0, stream>>>(
      q, gamma, beta, opart, mpart, lpart, S, out);
}